// Round 1
// baseline (3542.680 us; speedup 1.0000x reference)
//
#include <hip/hip_runtime.h>
#include <math.h>

// Problem constants (B=2, T=2048, C=2048, NH=16, HS=128, N_ELEM=64, A_T=10)
#define B_DIM 2
#define T_DIM 2048
#define C_DIM 2048
#define NHEAD 16
#define HS 128
#define QKV_N 6144          // 3*C
#define AT 10
#define M_DIM 4096          // B*T

// ---------------------------------------------------------------------------
// GEMM NT: C[M][N] = A[M][K] * B[N][K]^T + bias[N]   (A,B row-major, K contig)
// 128x128 tile, BK=16, 256 threads, 8x8 per thread.
// ---------------------------------------------------------------------------
#define BM 128
#define BN 128
#define BK 16

__global__ __launch_bounds__(256)
void gemm_nt_f32(const float* __restrict__ A, const float* __restrict__ Bm,
                 const float* __restrict__ bias, float* __restrict__ Cm,
                 int M, int N, int K) {
    __shared__ __align__(16) float As[BK][BM + 4];   // stored transposed: As[kk][m]
    __shared__ __align__(16) float Bs[BK][BN + 4];   // Bs[kk][n]

    const int tid = threadIdx.x;
    const int tx = tid & 15;       // n group
    const int ty = tid >> 4;       // m group
    const int m0 = blockIdx.y * BM;
    const int n0 = blockIdx.x * BN;

    float acc[8][8];
#pragma unroll
    for (int i = 0; i < 8; ++i)
#pragma unroll
        for (int j = 0; j < 8; ++j) acc[i][j] = 0.f;

    for (int k0 = 0; k0 < K; k0 += BK) {
        // stage A,B tiles (each 128 rows x 16 k): 512 float4 per tile, 2 per thread
#pragma unroll
        for (int t = 0; t < 2; ++t) {
            const int i   = tid + t * 256;
            const int row = i >> 2;
            const int kq  = (i & 3) * 4;
            float4 va = *(const float4*)&A[(size_t)(m0 + row) * K + k0 + kq];
            As[kq + 0][row] = va.x; As[kq + 1][row] = va.y;
            As[kq + 2][row] = va.z; As[kq + 3][row] = va.w;
            float4 vb = *(const float4*)&Bm[(size_t)(n0 + row) * K + k0 + kq];
            Bs[kq + 0][row] = vb.x; Bs[kq + 1][row] = vb.y;
            Bs[kq + 2][row] = vb.z; Bs[kq + 3][row] = vb.w;
        }
        __syncthreads();

#pragma unroll
        for (int kk = 0; kk < BK; ++kk) {
            float4 a0 = *(const float4*)&As[kk][ty * 4];
            float4 a1 = *(const float4*)&As[kk][64 + ty * 4];
            float4 b0 = *(const float4*)&Bs[kk][tx * 4];
            float4 b1 = *(const float4*)&Bs[kk][64 + tx * 4];
            float am[8] = {a0.x, a0.y, a0.z, a0.w, a1.x, a1.y, a1.z, a1.w};
            float bn[8] = {b0.x, b0.y, b0.z, b0.w, b1.x, b1.y, b1.z, b1.w};
#pragma unroll
            for (int i = 0; i < 8; ++i)
#pragma unroll
                for (int j = 0; j < 8; ++j)
                    acc[i][j] = fmaf(am[i], bn[j], acc[i][j]);
        }
        __syncthreads();
    }

    // epilogue: bias + store (M,N are multiples of 128 here)
#pragma unroll
    for (int i = 0; i < 8; ++i) {
        const int m = m0 + ((i < 4) ? (ty * 4 + i) : (64 + ty * 4 + i - 4));
        {
            const int n = n0 + tx * 4;
            float4 o;
            o.x = acc[i][0] + bias[n + 0];
            o.y = acc[i][1] + bias[n + 1];
            o.z = acc[i][2] + bias[n + 2];
            o.w = acc[i][3] + bias[n + 3];
            *(float4*)&Cm[(size_t)m * N + n] = o;
        }
        {
            const int n = n0 + 64 + tx * 4;
            float4 o;
            o.x = acc[i][4] + bias[n + 0];
            o.y = acc[i][5] + bias[n + 1];
            o.z = acc[i][6] + bias[n + 2];
            o.w = acc[i][7] + bias[n + 3];
            *(float4*)&Cm[(size_t)m * N + n] = o;
        }
    }
}

// ---------------------------------------------------------------------------
// RoPE in-place on q and k halves of the qkv buffer.
// qkv layout: [B*T][6144], head h at col h*384: q=[0,128) k=[128,256) v=[256,384)
// rope on first 64 dims of q and k: out[i]    = t[i]*cos[i]    - t[i+32]*sin[i]
//                                   out[i+32] = t[i+32]*cos[i+32] + t[i]*sin[i+32]
// one thread per (b,t,h,i<32) handles both q and k pairs.
// ---------------------------------------------------------------------------
__global__ __launch_bounds__(256)
void rope_kernel(float* __restrict__ qkv, const float* __restrict__ cosb,
                 const float* __restrict__ sinb) {
    const int idx = blockIdx.x * 256 + threadIdx.x;   // 2^21 total
    const int i = idx & 31;
    const int h = (idx >> 5) & 15;
    const int t = (idx >> 9) & 2047;
    const int b = idx >> 20;
    const size_t base = ((size_t)(b * T_DIM + t)) * QKV_N + h * 384;
    const float c1 = cosb[t * 64 + i],      s1 = sinb[t * 64 + i];
    const float c2 = cosb[t * 64 + 32 + i], s2 = sinb[t * 64 + 32 + i];

    float q1 = qkv[base + i], q2 = qkv[base + 32 + i];
    qkv[base + i]      = q1 * c1 - q2 * s1;
    qkv[base + 32 + i] = q2 * c2 + q1 * s2;

    float k1 = qkv[base + 128 + i], k2 = qkv[base + 160 + i];
    qkv[base + 128 + i] = k1 * c1 - k2 * s1;
    qkv[base + 160 + i] = k2 * c2 + k1 * s2;
}

// ---------------------------------------------------------------------------
// adapter qkv: aqkv[a][n] = sum_k wte[a][k]*attn_w[n][k] + attn_b[n]
// one wave per output column n; 10 accumulators; wave shuffle reduce.
// ---------------------------------------------------------------------------
__global__ __launch_bounds__(64)
void adapter_qkv_kernel(const float* __restrict__ wte, const float* __restrict__ w,
                        const float* __restrict__ bias, float* __restrict__ aqkv) {
    const int n = blockIdx.x;
    const int lane = threadIdx.x;
    float acc[AT];
#pragma unroll
    for (int a = 0; a < AT; ++a) acc[a] = 0.f;

    for (int k = lane * 4; k < C_DIM; k += 64 * 4) {
        float4 wv = *(const float4*)&w[(size_t)n * C_DIM + k];
#pragma unroll
        for (int a = 0; a < AT; ++a) {
            float4 tv = *(const float4*)&wte[(size_t)a * C_DIM + k];
            acc[a] += wv.x * tv.x + wv.y * tv.y + wv.z * tv.z + wv.w * tv.w;
        }
    }
#pragma unroll
    for (int a = 0; a < AT; ++a) {
        float v = acc[a];
        for (int off = 32; off; off >>= 1) v += __shfl_down(v, off);
        if (lane == 0) aqkv[(size_t)a * QKV_N + n] = v + bias[n];
    }
}

// ---------------------------------------------------------------------------
// Flash causal attention + fused adapter attention.
// One block per (b, h, 32-row q-tile). 256 threads: thread (r=tid>>3, c8=tid&7)
// owns row r, dims [c8*16, c8*16+16). Online softmax state per row replicated
// across the row's 8 lanes (kept consistent via identical shfl_xor reduces).
// P broadcast to the row's lanes via __shfl (no LDS round trip).
// Epilogue: 10-key adapter attention (no mask, no rope on ak) + gating, then
// write y in (B,T,C) layout for the proj GEMM.
// ---------------------------------------------------------------------------
__global__ __launch_bounds__(256)
void flash_attn_kernel(const float* __restrict__ qkv, const float* __restrict__ aqkv,
                       const float* __restrict__ gating, float* __restrict__ y) {
    __shared__ __align__(16) float Qs[32][132];
    __shared__ __align__(16) float Ks[32][132];
    __shared__ __align__(16) float Vs[32][132];

    const int tid = threadIdx.x;
    const int r   = tid >> 3;
    const int c8  = tid & 7;
    const int d0  = c8 * 16;
    const int qt  = blockIdx.x & 63;
    const int h   = (blockIdx.x >> 6) & 15;
    const int b   = blockIdx.x >> 10;
    const int q0  = qt * 32;
    const float scale = 0.08838834764831845f;   // 1/sqrt(128)

    // stage roped Q rows
    const size_t qbase = ((size_t)(b * T_DIM + q0 + r)) * QKV_N + h * 384;
#pragma unroll
    for (int j = 0; j < 4; ++j)
        *(float4*)&Qs[r][d0 + j * 4] = *(const float4*)&qkv[qbase + d0 + j * 4];

    float acc[16];
#pragma unroll
    for (int dd = 0; dd < 16; ++dd) acc[dd] = 0.f;
    float mrow = -INFINITY, lrow = 0.f;
    const int lanebase = (r & 7) * 8;   // row's lane group base within the wave

    for (int k0 = 0; k0 <= q0; k0 += 32) {
        __syncthreads();   // protect Ks/Vs (and Qs on first iter)
        const size_t kbase = ((size_t)(b * T_DIM + k0 + r)) * QKV_N + h * 384;
#pragma unroll
        for (int j = 0; j < 4; ++j) {
            *(float4*)&Ks[r][d0 + j * 4] = *(const float4*)&qkv[kbase + 128 + d0 + j * 4];
            *(float4*)&Vs[r][d0 + j * 4] = *(const float4*)&qkv[kbase + 256 + d0 + j * 4];
        }
        __syncthreads();

        // S: thread computes s[r][k] for k = c8 + 8*jj
        float sv[4] = {0.f, 0.f, 0.f, 0.f};
#pragma unroll 8
        for (int kk = 0; kk < HS; kk += 4) {
            float4 qv = *(const float4*)&Qs[r][kk];
#pragma unroll
            for (int jj = 0; jj < 4; ++jj) {
                const int k = c8 + jj * 8;
                float4 kv = *(const float4*)&Ks[k][kk];
                sv[jj] = fmaf(qv.x, kv.x, fmaf(qv.y, kv.y,
                         fmaf(qv.z, kv.z, fmaf(qv.w, kv.w, sv[jj]))));
            }
        }
        // scale + causal mask + tile max
        float tmax = -INFINITY;
#pragma unroll
        for (int jj = 0; jj < 4; ++jj) {
            const int k = c8 + jj * 8;
            sv[jj] *= scale;
            if (k0 + k > q0 + r) sv[jj] = -INFINITY;
            tmax = fmaxf(tmax, sv[jj]);
        }
        tmax = fmaxf(tmax, __shfl_xor(tmax, 1));
        tmax = fmaxf(tmax, __shfl_xor(tmax, 2));
        tmax = fmaxf(tmax, __shfl_xor(tmax, 4));
        const float mnew  = fmaxf(mrow, tmax);
        const float alpha = expf(mrow - mnew);   // first iter: exp(-inf)=0

        float pv[4], psum = 0.f;
#pragma unroll
        for (int jj = 0; jj < 4; ++jj) {
            pv[jj] = expf(sv[jj] - mnew);        // masked -> exp(-inf)=0
            psum += pv[jj];
        }
        psum += __shfl_xor(psum, 1);
        psum += __shfl_xor(psum, 2);
        psum += __shfl_xor(psum, 4);
        lrow = lrow * alpha + psum;
        mrow = mnew;

#pragma unroll
        for (int dd = 0; dd < 16; ++dd) acc[dd] *= alpha;

        // PV: broadcast p[k] from the owning lane, FMA against Vs
#pragma unroll
        for (int jj = 0; jj < 4; ++jj) {
#pragma unroll
            for (int c = 0; c < 8; ++c) {
                const float pk = __shfl(pv[jj], lanebase + c);
                const int k = jj * 8 + c;
#pragma unroll
                for (int dq = 0; dq < 4; ++dq) {
                    float4 vv = *(const float4*)&Vs[k][d0 + dq * 4];
                    acc[dq * 4 + 0] = fmaf(pk, vv.x, acc[dq * 4 + 0]);
                    acc[dq * 4 + 1] = fmaf(pk, vv.y, acc[dq * 4 + 1]);
                    acc[dq * 4 + 2] = fmaf(pk, vv.z, acc[dq * 4 + 2]);
                    acc[dq * 4 + 3] = fmaf(pk, vv.w, acc[dq * 4 + 3]);
                }
            }
        }
    }

    // normalize
    const float inv = 1.f / lrow;
#pragma unroll
    for (int dd = 0; dd < 16; ++dd) acc[dd] *= inv;

    // ---- adapter attention (10 keys, unmasked) ----
    __syncthreads();   // done with Ks/Vs main use
    if (tid < 80) {
        const int a = tid >> 3, c = tid & 7;
#pragma unroll
        for (int j = 0; j < 4; ++j) {
            *(float4*)&Ks[a][c * 16 + j * 4] =
                *(const float4*)&aqkv[(size_t)a * QKV_N + h * 384 + 128 + c * 16 + j * 4];
            *(float4*)&Vs[a][c * 16 + j * 4] =
                *(const float4*)&aqkv[(size_t)a * QKV_N + h * 384 + 256 + c * 16 + j * 4];
        }
    }
    __syncthreads();

    float sa[AT];
#pragma unroll
    for (int a = 0; a < AT; ++a) {
        float partial = 0.f;
#pragma unroll
        for (int dq = 0; dq < 4; ++dq) {
            float4 qv = *(const float4*)&Qs[r][d0 + dq * 4];
            float4 kv = *(const float4*)&Ks[a][d0 + dq * 4];
            partial += qv.x * kv.x + qv.y * kv.y + qv.z * kv.z + qv.w * kv.w;
        }
        partial += __shfl_xor(partial, 1);
        partial += __shfl_xor(partial, 2);
        partial += __shfl_xor(partial, 4);
        sa[a] = partial * scale;
    }
    float amax = sa[0];
#pragma unroll
    for (int a = 1; a < AT; ++a) amax = fmaxf(amax, sa[a]);
    float asum = 0.f;
#pragma unroll
    for (int a = 0; a < AT; ++a) { sa[a] = expf(sa[a] - amax); asum += sa[a]; }
    const float gf = gating[0] / asum;

#pragma unroll
    for (int dq = 0; dq < 4; ++dq) {
        float ax = 0.f, ay_ = 0.f, az = 0.f, aw = 0.f;
#pragma unroll
        for (int a = 0; a < AT; ++a) {
            float4 vv = *(const float4*)&Vs[a][d0 + dq * 4];
            ax = fmaf(sa[a], vv.x, ax);
            ay_ = fmaf(sa[a], vv.y, ay_);
            az = fmaf(sa[a], vv.z, az);
            aw = fmaf(sa[a], vv.w, aw);
        }
        acc[dq * 4 + 0] += gf * ax;
        acc[dq * 4 + 1] += gf * ay_;
        acc[dq * 4 + 2] += gf * az;
        acc[dq * 4 + 3] += gf * aw;
    }

    // write y in (B,T,C) layout
    const size_t ybase = ((size_t)(b * T_DIM + q0 + r)) * C_DIM + h * HS + d0;
#pragma unroll
    for (int dq = 0; dq < 4; ++dq) {
        float4 o = {acc[dq * 4 + 0], acc[dq * 4 + 1], acc[dq * 4 + 2], acc[dq * 4 + 3]};
        *(float4*)&y[ybase + dq * 4] = o;
    }
}

// ---------------------------------------------------------------------------
extern "C" void kernel_launch(void* const* d_in, const int* in_sizes, int n_in,
                              void* d_out, int out_size, void* d_ws, size_t ws_size,
                              hipStream_t stream) {
    const float* x       = (const float*)d_in[0];
    const float* cosb    = (const float*)d_in[1];
    const float* sinb    = (const float*)d_in[2];
    // d_in[3] = mask (bool) — causal, unused
    const float* attn_w  = (const float*)d_in[4];
    const float* attn_b  = (const float*)d_in[5];
    const float* proj_w  = (const float*)d_in[6];
    const float* proj_b  = (const float*)d_in[7];
    const float* wte     = (const float*)d_in[8];
    const float* gating  = (const float*)d_in[9];
    float* out = (float*)d_out;

    // workspace: qkv (4096*6144 f32 = 100.7MB) | y (4096*2048 = 33.5MB) | aqkv (10*6144)
    float* qkv  = (float*)d_ws;
    float* y    = qkv + (size_t)M_DIM * QKV_N;
    float* aqkv = y + (size_t)M_DIM * C_DIM;

    // 1. qkv = x @ attn_w^T + attn_b
    gemm_nt_f32<<<dim3(QKV_N / BN, M_DIM / BM), 256, 0, stream>>>(
        x, attn_w, attn_b, qkv, M_DIM, QKV_N, C_DIM);
    // 2. RoPE in place on q,k
    rope_kernel<<<(B_DIM * T_DIM * NHEAD * 32) / 256, 256, 0, stream>>>(qkv, cosb, sinb);
    // 3. adapter qkv (tiny GEMM)
    adapter_qkv_kernel<<<QKV_N, 64, 0, stream>>>(wte, attn_w, attn_b, aqkv);
    // 4. flash causal attention + adapter attention + gating -> y (B,T,C)
    flash_attn_kernel<<<B_DIM * NHEAD * (T_DIM / 32), 256, 0, stream>>>(qkv, aqkv, gating, y);
    // 5. out = y @ proj_w^T + proj_b
    gemm_nt_f32<<<dim3(C_DIM / BN, M_DIM / BM), 256, 0, stream>>>(
        y, proj_w, proj_b, out, M_DIM, C_DIM, C_DIM);
}

// Round 2
// 1778.645 us; speedup vs baseline: 1.9918x; 1.9918x over previous
//
#include <hip/hip_runtime.h>
#include <math.h>

// Problem constants (B=2, T=2048, C=2048, NH=16, HS=128, N_ELEM=64, A_T=10)
#define B_DIM 2
#define T_DIM 2048
#define C_DIM 2048
#define NHEAD 16
#define HS 128
#define QKV_N 6144          // 3*C
#define AT 10
#define M_DIM 4096          // B*T

using bf16x8 = __attribute__((ext_vector_type(8))) short;
using f32x4v = __attribute__((ext_vector_type(4))) float;

__device__ __forceinline__ unsigned short f2bf(float f) {
    union { float f; unsigned int u; } cv; cv.f = f;
    unsigned int u = cv.u;
    return (unsigned short)((u + 0x7FFFu + ((u >> 16) & 1u)) >> 16);
}

__device__ __forceinline__ float dot4(const float4 a, const float4 b, float acc) {
    return fmaf(a.x, b.x, fmaf(a.y, b.y, fmaf(a.z, b.z, fmaf(a.w, b.w, acc))));
}
__device__ __forceinline__ void fma4(float4& acc, float p, const float4 v) {
    acc.x = fmaf(p, v.x, acc.x); acc.y = fmaf(p, v.y, acc.y);
    acc.z = fmaf(p, v.z, acc.z); acc.w = fmaf(p, v.w, acc.w);
}
__device__ __forceinline__ void scale4(float4& a, float s) {
    a.x *= s; a.y *= s; a.z *= s; a.w *= s;
}

__device__ __forceinline__ void gload_lds16(const void* g, void* l) {
    __builtin_amdgcn_global_load_lds(
        (const __attribute__((address_space(1))) void*)g,
        (__attribute__((address_space(3))) void*)l, 16, 0, 0);
}

// ---------------------------------------------------------------------------
// f32 -> bf16 convert (vectorized, 8 elems/thread)
// ---------------------------------------------------------------------------
__global__ __launch_bounds__(256)
void f32_to_bf16_kernel(const float* __restrict__ in, unsigned short* __restrict__ out, int n8) {
    const int i = blockIdx.x * 256 + threadIdx.x;
    if (i >= n8) return;
    const float4 a = *(const float4*)&in[(size_t)i * 8];
    const float4 b = *(const float4*)&in[(size_t)i * 8 + 4];
    ushort4 o0 = make_ushort4(f2bf(a.x), f2bf(a.y), f2bf(a.z), f2bf(a.w));
    ushort4 o1 = make_ushort4(f2bf(b.x), f2bf(b.y), f2bf(b.z), f2bf(b.w));
    *(ushort4*)&out[(size_t)i * 8] = o0;
    *(ushort4*)&out[(size_t)i * 8 + 4] = o1;
}

// ---------------------------------------------------------------------------
// bf16 MFMA GEMM NT: C[M][N] = A[M][K] * B[N][K]^T + bias[N]
// m97 structure: 128x128 tile, BK=32, 256 thr (4 waves), global_load_lds w=16,
// each wave 64x64 out = 4x4 frags of mfma_f32_16x16x32_bf16.
// Fragment layout (verified m89/m91): A/B lane l holds row/col (l&15),
// k = (l>>4)*8 + j (8 contiguous bf16 = one ds_read_b128).
// C/D: col = l&15, row = (l>>4)*4 + reg.
// ---------------------------------------------------------------------------
__global__ __launch_bounds__(256)
void gemm_nt_mfma(const unsigned short* __restrict__ A, const unsigned short* __restrict__ Bw,
                  const float* __restrict__ bias, float* __restrict__ C,
                  int M, int N, int K) {
    __shared__ unsigned short As[128 * 32];
    __shared__ unsigned short Bs[128 * 32];

    const int tid  = threadIdx.x;
    const int wave = tid >> 6;
    const int lane = tid & 63;
    const int m0 = blockIdx.y * 128;
    const int n0 = blockIdx.x * 128;
    const int wr = (wave >> 1) * 64;
    const int wc = (wave & 1) * 64;

    f32x4v acc[4][4];
#pragma unroll
    for (int i = 0; i < 4; ++i)
#pragma unroll
        for (int j = 0; j < 4; ++j)
#pragma unroll
            for (int q = 0; q < 4; ++q) acc[i][j][q] = 0.f;

    const int srow = lane >> 2;            // staging: row within 16-row segment
    const int sk   = (lane & 3) * 8;       // staging: k offset (8 bf16 = 16B)
    const int fr   = lane & 15;            // fragment row/col
    const int fk   = (lane >> 4) * 8;      // fragment k offset

    for (int k0 = 0; k0 < K; k0 += 32) {
        __syncthreads();
#pragma unroll
        for (int t = 0; t < 2; ++t) {
            const int seg = wave * 2 + t;  // 8 segments of 16 rows
            const unsigned short* ga = &A[(size_t)(m0 + seg * 16 + srow) * K + k0 + sk];
            const unsigned short* gb = &Bw[(size_t)(n0 + seg * 16 + srow) * K + k0 + sk];
            gload_lds16(ga, &As[seg * 512]);
            gload_lds16(gb, &Bs[seg * 512]);
        }
        __syncthreads();   // compiler drains vmcnt before s_barrier

        bf16x8 af[4], bfg[4];
#pragma unroll
        for (int i = 0; i < 4; ++i)
            af[i] = *(const bf16x8*)&As[(wr + i * 16 + fr) * 32 + fk];
#pragma unroll
        for (int j = 0; j < 4; ++j)
            bfg[j] = *(const bf16x8*)&Bs[(wc + j * 16 + fr) * 32 + fk];
#pragma unroll
        for (int i = 0; i < 4; ++i)
#pragma unroll
            for (int j = 0; j < 4; ++j)
                acc[i][j] = __builtin_amdgcn_mfma_f32_16x16x32_bf16(af[i], bfg[j], acc[i][j], 0, 0, 0);
    }

    const int r4 = (lane >> 4) * 4;
#pragma unroll
    for (int i = 0; i < 4; ++i) {
#pragma unroll
        for (int j = 0; j < 4; ++j) {
            const int col = n0 + wc + j * 16 + fr;
            const float bv = bias[col];
#pragma unroll
            for (int q = 0; q < 4; ++q) {
                const int row = m0 + wr + i * 16 + r4 + q;
                C[(size_t)row * N + col] = acc[i][j][q] + bv;
            }
        }
    }
}

// ---------------------------------------------------------------------------
// RoPE in-place on q and k halves of the qkv buffer (unchanged, verified R1).
// ---------------------------------------------------------------------------
__global__ __launch_bounds__(256)
void rope_kernel(float* __restrict__ qkv, const float* __restrict__ cosb,
                 const float* __restrict__ sinb) {
    const int idx = blockIdx.x * 256 + threadIdx.x;   // 2^21 total
    const int i = idx & 31;
    const int h = (idx >> 5) & 15;
    const int t = (idx >> 9) & 2047;
    const int b = idx >> 20;
    const size_t base = ((size_t)(b * T_DIM + t)) * QKV_N + h * 384;
    const float c1 = cosb[t * 64 + i],      s1 = sinb[t * 64 + i];
    const float c2 = cosb[t * 64 + 32 + i], s2 = sinb[t * 64 + 32 + i];

    float q1 = qkv[base + i], q2 = qkv[base + 32 + i];
    qkv[base + i]      = q1 * c1 - q2 * s1;
    qkv[base + 32 + i] = q2 * c2 + q1 * s2;

    float k1 = qkv[base + 128 + i], k2 = qkv[base + 160 + i];
    qkv[base + 128 + i] = k1 * c1 - k2 * s1;
    qkv[base + 160 + i] = k2 * c2 + k1 * s2;
}

// ---------------------------------------------------------------------------
// adapter qkv (tiny, fp32, unchanged, verified R1)
// ---------------------------------------------------------------------------
__global__ __launch_bounds__(64)
void adapter_qkv_kernel(const float* __restrict__ wte, const float* __restrict__ w,
                        const float* __restrict__ bias, float* __restrict__ aqkv) {
    const int n = blockIdx.x;
    const int lane = threadIdx.x;
    float acc[AT];
#pragma unroll
    for (int a = 0; a < AT; ++a) acc[a] = 0.f;

    for (int k = lane * 4; k < C_DIM; k += 64 * 4) {
        float4 wv = *(const float4*)&w[(size_t)n * C_DIM + k];
#pragma unroll
        for (int a = 0; a < AT; ++a) {
            float4 tv = *(const float4*)&wte[(size_t)a * C_DIM + k];
            acc[a] += wv.x * tv.x + wv.y * tv.y + wv.z * tv.z + wv.w * tv.w;
        }
    }
#pragma unroll
    for (int a = 0; a < AT; ++a) {
        float v = acc[a];
        for (int off = 32; off; off >>= 1) v += __shfl_down(v, off);
        if (lane == 0) aqkv[(size_t)a * QKV_N + n] = v + bias[n];
    }
}

// ---------------------------------------------------------------------------
// Flash causal attention v2 (fp32) + fused adapter attention, writes y as bf16.
// 512 threads, q-tile 64, k-tile 32.
// S phase: thread (rq=tid>>4, kq=tid&15) owns rows {2rq,2rq+1} x k {kq,kq+16},
//   2x2 register blocking. Row softmax state reduced over the 16 kq lanes
//   (intra-wave shfl_xor 1/2/4/8).
// P handoff via LDS Ps[64][36] -- written and read by the SAME 16-lane group
//   (intra-wave, no barrier needed).
// PV phase: thread (rq, dp=tid&15) owns rows {2rq,2rq+1} x d {dp*4..+4, 64+dp*4..+4}
//   -> V reads span 256B contiguous across lanes (2-way bank alias = free).
// ---------------------------------------------------------------------------
__global__ __launch_bounds__(512)
void flash_attn2(const float* __restrict__ qkv, const float* __restrict__ aqkv,
                 const float* __restrict__ gating, unsigned short* __restrict__ yb) {
    __shared__ __align__(16) float Qs[64][132];
    __shared__ __align__(16) float Ks[32][132];
    __shared__ __align__(16) float Vs[32][132];
    __shared__ __align__(16) float Ps[64][36];

    const int tid = threadIdx.x;
    const int qt = blockIdx.x & 31;
    const int h  = (blockIdx.x >> 5) & 15;
    const int b  = blockIdx.x >> 9;
    const int q0 = qt * 64;
    const float scale = 0.08838834764831845f;   // 1/sqrt(128)

    const int rq = tid >> 4;      // 0..31
    const int kq = tid & 15;      // S-phase k, PV-phase dp (same lanes)
    const int dp = kq;

    // stage Q (64 rows x 128): thread (r=tid>>3, c=tid&7) copies 4 float4
    {
        const int r = tid >> 3, c = tid & 7;
        const size_t qb = ((size_t)(b * T_DIM + q0 + r)) * QKV_N + h * 384;
#pragma unroll
        for (int j = 0; j < 4; ++j)
            *(float4*)&Qs[r][c * 16 + j * 4] = *(const float4*)&qkv[qb + c * 16 + j * 4];
    }

    float4 a0lo = {0,0,0,0}, a0hi = {0,0,0,0}, a1lo = {0,0,0,0}, a1hi = {0,0,0,0};
    float mrow0 = -INFINITY, mrow1 = -INFINITY, lrow0 = 0.f, lrow1 = 0.f;

    const int ktiles = qt * 2 + 2;
    for (int kt = 0; kt < ktiles; ++kt) {
        const int k0 = kt * 32;
        __syncthreads();
        // stage K,V (32 rows x 128 each): thread (r=tid>>4, c=tid&15) 2 float4 each
        {
            const int r = tid >> 4, c = tid & 15;
            const size_t kb = ((size_t)(b * T_DIM + k0 + r)) * QKV_N + h * 384;
            *(float4*)&Ks[r][c * 8]     = *(const float4*)&qkv[kb + 128 + c * 8];
            *(float4*)&Ks[r][c * 8 + 4] = *(const float4*)&qkv[kb + 128 + c * 8 + 4];
            *(float4*)&Vs[r][c * 8]     = *(const float4*)&qkv[kb + 256 + c * 8];
            *(float4*)&Vs[r][c * 8 + 4] = *(const float4*)&qkv[kb + 256 + c * 8 + 4];
        }
        __syncthreads();

        // ---- S: 2x2 register-blocked dot products ----
        float s00 = 0.f, s01 = 0.f, s10 = 0.f, s11 = 0.f;
#pragma unroll 4
        for (int kk = 0; kk < HS; kk += 4) {
            const float4 qa = *(const float4*)&Qs[2 * rq][kk];
            const float4 qb = *(const float4*)&Qs[2 * rq + 1][kk];
            const float4 ka = *(const float4*)&Ks[kq][kk];
            const float4 kb = *(const float4*)&Ks[kq + 16][kk];
            s00 = dot4(qa, ka, s00);
            s01 = dot4(qa, kb, s01);
            s10 = dot4(qb, ka, s10);
            s11 = dot4(qb, kb, s11);
        }
        s00 *= scale; s01 *= scale; s10 *= scale; s11 *= scale;

        if (kt >= ktiles - 2) {   // only the last two tiles touch the diagonal
            const int row0 = q0 + 2 * rq, row1 = row0 + 1;
            if (k0 + kq > row0)      s00 = -INFINITY;
            if (k0 + kq + 16 > row0) s01 = -INFINITY;
            if (k0 + kq > row1)      s10 = -INFINITY;
            if (k0 + kq + 16 > row1) s11 = -INFINITY;
        }

        float mx0 = fmaxf(s00, s01), mx1 = fmaxf(s10, s11);
#pragma unroll
        for (int off = 1; off < 16; off <<= 1) {
            mx0 = fmaxf(mx0, __shfl_xor(mx0, off));
            mx1 = fmaxf(mx1, __shfl_xor(mx1, off));
        }
        const float mn0 = fmaxf(mrow0, mx0), mn1 = fmaxf(mrow1, mx1);
        const float al0 = __expf(mrow0 - mn0), al1 = __expf(mrow1 - mn1);
        const float p00 = __expf(s00 - mn0), p01 = __expf(s01 - mn0);
        const float p10 = __expf(s10 - mn1), p11 = __expf(s11 - mn1);
        float ps0 = p00 + p01, ps1 = p10 + p11;
#pragma unroll
        for (int off = 1; off < 16; off <<= 1) {
            ps0 += __shfl_xor(ps0, off);
            ps1 += __shfl_xor(ps1, off);
        }
        lrow0 = lrow0 * al0 + ps0;
        lrow1 = lrow1 * al1 + ps1;
        mrow0 = mn0; mrow1 = mn1;

        Ps[2 * rq][kq]          = p00;
        Ps[2 * rq][kq + 16]     = p01;
        Ps[2 * rq + 1][kq]      = p10;
        Ps[2 * rq + 1][kq + 16] = p11;

        scale4(a0lo, al0); scale4(a0hi, al0);
        scale4(a1lo, al1); scale4(a1hi, al1);

        // ---- PV: intra-wave read-back of Ps (same 16-lane group wrote it) ----
#define PVSTEP(KIDX, PC0, PC1) {                                    \
            const float4 v0 = *(const float4*)&Vs[(KIDX)][dp * 4];       \
            const float4 v1 = *(const float4*)&Vs[(KIDX)][64 + dp * 4];  \
            fma4(a0lo, (PC0), v0); fma4(a0hi, (PC0), v1);                \
            fma4(a1lo, (PC1), v0); fma4(a1hi, (PC1), v1); }
#pragma unroll 2
        for (int kk = 0; kk < 32; kk += 4) {
            const float4 pa = *(const float4*)&Ps[2 * rq][kk];
            const float4 pb = *(const float4*)&Ps[2 * rq + 1][kk];
            PVSTEP(kk + 0, pa.x, pb.x);
            PVSTEP(kk + 1, pa.y, pb.y);
            PVSTEP(kk + 2, pa.z, pb.z);
            PVSTEP(kk + 3, pa.w, pb.w);
        }
#undef PVSTEP
    }

    // normalize main attention
    const float inv0 = 1.f / lrow0, inv1 = 1.f / lrow1;
    scale4(a0lo, inv0); scale4(a0hi, inv0);
    scale4(a1lo, inv1); scale4(a1hi, inv1);

    // ---- adapter attention (10 keys, unmasked, own softmax) ----
    __syncthreads();   // done with Ks/Vs
    if (tid < 320) {
        const int a = tid >> 5, c = tid & 31;
        const size_t ab = (size_t)a * QKV_N + h * 384;
        *(float4*)&Ks[a][c * 4] = *(const float4*)&aqkv[ab + 128 + c * 4];
        *(float4*)&Vs[a][c * 4] = *(const float4*)&aqkv[ab + 256 + c * 4];
    }
    __syncthreads();

    const float4 q0lo = *(const float4*)&Qs[2 * rq][dp * 4];
    const float4 q0hi = *(const float4*)&Qs[2 * rq][64 + dp * 4];
    const float4 q1lo = *(const float4*)&Qs[2 * rq + 1][dp * 4];
    const float4 q1hi = *(const float4*)&Qs[2 * rq + 1][64 + dp * 4];

    float w0[AT], w1[AT];
#pragma unroll
    for (int a = 0; a < AT; ++a) {
        const float4 klo = *(const float4*)&Ks[a][dp * 4];
        const float4 khi = *(const float4*)&Ks[a][64 + dp * 4];
        float t0 = dot4(q0lo, klo, 0.f); t0 = dot4(q0hi, khi, t0);
        float t1 = dot4(q1lo, klo, 0.f); t1 = dot4(q1hi, khi, t1);
#pragma unroll
        for (int off = 1; off < 16; off <<= 1) {
            t0 += __shfl_xor(t0, off);
            t1 += __shfl_xor(t1, off);
        }
        w0[a] = t0 * scale;
        w1[a] = t1 * scale;
    }
    float am0 = w0[0], am1 = w1[0];
#pragma unroll
    for (int a = 1; a < AT; ++a) { am0 = fmaxf(am0, w0[a]); am1 = fmaxf(am1, w1[a]); }
    float as0 = 0.f, as1 = 0.f;
#pragma unroll
    for (int a = 0; a < AT; ++a) {
        w0[a] = __expf(w0[a] - am0); as0 += w0[a];
        w1[a] = __expf(w1[a] - am1); as1 += w1[a];
    }
    const float g = gating[0];
    const float g0 = g / as0, g1 = g / as1;
#pragma unroll
    for (int a = 0; a < AT; ++a) {
        const float4 vlo = *(const float4*)&Vs[a][dp * 4];
        const float4 vhi = *(const float4*)&Vs[a][64 + dp * 4];
        fma4(a0lo, g0 * w0[a], vlo); fma4(a0hi, g0 * w0[a], vhi);
        fma4(a1lo, g1 * w1[a], vlo); fma4(a1hi, g1 * w1[a], vhi);
    }

    // write y as bf16 in (B,T,C) layout
    const size_t y0 = ((size_t)(b * T_DIM + q0 + 2 * rq)) * C_DIM + h * HS;
    const size_t y1 = y0 + C_DIM;
    *(ushort4*)&yb[y0 + dp * 4]      = make_ushort4(f2bf(a0lo.x), f2bf(a0lo.y), f2bf(a0lo.z), f2bf(a0lo.w));
    *(ushort4*)&yb[y0 + 64 + dp * 4] = make_ushort4(f2bf(a0hi.x), f2bf(a0hi.y), f2bf(a0hi.z), f2bf(a0hi.w));
    *(ushort4*)&yb[y1 + dp * 4]      = make_ushort4(f2bf(a1lo.x), f2bf(a1lo.y), f2bf(a1lo.z), f2bf(a1lo.w));
    *(ushort4*)&yb[y1 + 64 + dp * 4] = make_ushort4(f2bf(a1hi.x), f2bf(a1hi.y), f2bf(a1hi.z), f2bf(a1hi.w));
}

// ---------------------------------------------------------------------------
extern "C" void kernel_launch(void* const* d_in, const int* in_sizes, int n_in,
                              void* d_out, int out_size, void* d_ws, size_t ws_size,
                              hipStream_t stream) {
    const float* x       = (const float*)d_in[0];
    const float* cosb    = (const float*)d_in[1];
    const float* sinb    = (const float*)d_in[2];
    // d_in[3] = mask (bool) — causal, unused
    const float* attn_w  = (const float*)d_in[4];
    const float* attn_b  = (const float*)d_in[5];
    const float* proj_w  = (const float*)d_in[6];
    const float* proj_b  = (const float*)d_in[7];
    const float* wte     = (const float*)d_in[8];
    const float* gating  = (const float*)d_in[9];
    float* out = (float*)d_out;

    // workspace layout (142.9 MB total, with live-range aliasing):
    //   qkv  f32  [4096*6144]                      100.66 MB
    //   aqkv f32  [10*6144]                          0.25 MB
    //   xb   bf16 [4096*2048]   (reused for pwb)    16.78 MB
    //   awb  bf16 [6144*2048]   (reused for yb)     25.17 MB
    float* qkv  = (float*)d_ws;
    float* aqkv = qkv + (size_t)M_DIM * QKV_N;
    unsigned short* xb  = (unsigned short*)(aqkv + (size_t)AT * QKV_N);
    unsigned short* awb = xb + (size_t)M_DIM * C_DIM;
    unsigned short* pwb = xb;    // alive only after GEMM1 (stream-ordered)
    unsigned short* yb  = awb;   // alive only after GEMM1

    // 1. convert x, attn_w to bf16
    f32_to_bf16_kernel<<<(M_DIM * C_DIM / 8 + 255) / 256, 256, 0, stream>>>(x, xb, M_DIM * C_DIM / 8);
    f32_to_bf16_kernel<<<(QKV_N * C_DIM / 8 + 255) / 256, 256, 0, stream>>>(attn_w, awb, QKV_N * C_DIM / 8);
    // 2. qkv = x @ attn_w^T + attn_b   (bf16 MFMA, fp32 out)
    gemm_nt_mfma<<<dim3(QKV_N / 128, M_DIM / 128), 256, 0, stream>>>(
        xb, awb, attn_b, qkv, M_DIM, QKV_N, C_DIM);
    // 3. convert proj_w (into xb space — xb dead after GEMM1)
    f32_to_bf16_kernel<<<(C_DIM * C_DIM / 8 + 255) / 256, 256, 0, stream>>>(proj_w, pwb, C_DIM * C_DIM / 8);
    // 4. RoPE in place on q,k
    rope_kernel<<<(B_DIM * T_DIM * NHEAD * 32) / 256, 256, 0, stream>>>(qkv, cosb, sinb);
    // 5. adapter qkv (tiny fp32 GEMM)
    adapter_qkv_kernel<<<QKV_N, 64, 0, stream>>>(wte, attn_w, attn_b, aqkv);
    // 6. flash causal attention + adapter attention + gating -> yb (bf16, B,T,C)
    flash_attn2<<<B_DIM * NHEAD * (T_DIM / 64), 512, 0, stream>>>(qkv, aqkv, gating, yb);
    // 7. out = y @ proj_w^T + proj_b   (bf16 MFMA, fp32 out)
    gemm_nt_mfma<<<dim3(C_DIM / 128, M_DIM / 128), 256, 0, stream>>>(
        yb, pwb, proj_b, out, M_DIM, C_DIM, C_DIM);
}

// Round 4
// 531.141 us; speedup vs baseline: 6.6699x; 3.3487x over previous
//
#include <hip/hip_runtime.h>
#include <math.h>

// Problem constants (B=2, T=2048, C=2048, NH=16, HS=128, N_ELEM=64, A_T=10)
#define B_DIM 2
#define T_DIM 2048
#define C_DIM 2048
#define NHEAD 16
#define HS 128
#define QKV_N 6144          // 3*C
#define AT 10
#define M_DIM 4096          // B*T

using bf16x8 = __attribute__((ext_vector_type(8))) short;
using f32x4v = __attribute__((ext_vector_type(4))) float;

__device__ __forceinline__ unsigned short f2bf(float f) {
    union { float f; unsigned int u; } cv; cv.f = f;
    unsigned int u = cv.u;
    return (unsigned short)((u + 0x7FFFu + ((u >> 16) & 1u)) >> 16);
}
__device__ __forceinline__ float bf2f(unsigned short h) {
    union { unsigned int u; float f; } cv; cv.u = ((unsigned int)h) << 16;
    return cv.f;
}
__device__ __forceinline__ unsigned int pack_bf16(float lo, float hi) {
    unsigned int r;
    asm volatile("v_cvt_pk_bf16_f32 %0, %1, %2" : "=v"(r) : "v"(lo), "v"(hi));
    return r;
}
__device__ __forceinline__ void gload_lds16(const void* g, void* l) {
    __builtin_amdgcn_global_load_lds(
        (const __attribute__((address_space(1))) void*)g,
        (__attribute__((address_space(3))) void*)l, 16, 0, 0);
}

// ---------------------------------------------------------------------------
// f32 -> bf16 convert (8 elems/thread)
// ---------------------------------------------------------------------------
__global__ __launch_bounds__(256)
void f32_to_bf16_kernel(const float* __restrict__ in, unsigned short* __restrict__ out, int n8) {
    const int i = blockIdx.x * 256 + threadIdx.x;
    if (i >= n8) return;
    const float4 a = *(const float4*)&in[(size_t)i * 8];
    const float4 b = *(const float4*)&in[(size_t)i * 8 + 4];
    *(ushort4*)&out[(size_t)i * 8]     = make_ushort4(f2bf(a.x), f2bf(a.y), f2bf(a.z), f2bf(a.w));
    *(ushort4*)&out[(size_t)i * 8 + 4] = make_ushort4(f2bf(b.x), f2bf(b.y), f2bf(b.z), f2bf(b.w));
}

// ---------------------------------------------------------------------------
// bf16 MFMA GEMM NT: C[M][N] = A[M][K]*B[N][K]^T + bias[N]. Out f32 or bf16.
// m97 structure (verified R2): 128x128 tile, BK=32, 4 waves, global_load_lds w16.
// ---------------------------------------------------------------------------
template<int BF16OUT>
__global__ __launch_bounds__(256)
void gemm_nt_mfma(const unsigned short* __restrict__ A, const unsigned short* __restrict__ Bw,
                  const float* __restrict__ bias, void* __restrict__ Cout,
                  int M, int N, int K) {
    __shared__ unsigned short As[128 * 32];
    __shared__ unsigned short Bs[128 * 32];

    const int tid  = threadIdx.x;
    const int wave = tid >> 6;
    const int lane = tid & 63;
    const int m0 = blockIdx.y * 128;
    const int n0 = blockIdx.x * 128;
    const int wr = (wave >> 1) * 64;
    const int wc = (wave & 1) * 64;

    f32x4v acc[4][4];
#pragma unroll
    for (int i = 0; i < 4; ++i)
#pragma unroll
        for (int j = 0; j < 4; ++j)
#pragma unroll
            for (int q = 0; q < 4; ++q) acc[i][j][q] = 0.f;

    const int srow = lane >> 2;
    const int sk   = (lane & 3) * 8;
    const int fr   = lane & 15;
    const int fk   = (lane >> 4) * 8;

    for (int k0 = 0; k0 < K; k0 += 32) {
        __syncthreads();
#pragma unroll
        for (int t = 0; t < 2; ++t) {
            const int seg = wave * 2 + t;
            gload_lds16(&A[(size_t)(m0 + seg * 16 + srow) * K + k0 + sk], &As[seg * 512]);
            gload_lds16(&Bw[(size_t)(n0 + seg * 16 + srow) * K + k0 + sk], &Bs[seg * 512]);
        }
        __syncthreads();

        bf16x8 af[4], bfg[4];
#pragma unroll
        for (int i = 0; i < 4; ++i)
            af[i] = *(const bf16x8*)&As[(wr + i * 16 + fr) * 32 + fk];
#pragma unroll
        for (int j = 0; j < 4; ++j)
            bfg[j] = *(const bf16x8*)&Bs[(wc + j * 16 + fr) * 32 + fk];
#pragma unroll
        for (int i = 0; i < 4; ++i)
#pragma unroll
            for (int j = 0; j < 4; ++j)
                acc[i][j] = __builtin_amdgcn_mfma_f32_16x16x32_bf16(af[i], bfg[j], acc[i][j], 0, 0, 0);
    }

    const int r4 = (lane >> 4) * 4;
#pragma unroll
    for (int i = 0; i < 4; ++i) {
#pragma unroll
        for (int j = 0; j < 4; ++j) {
            const int col = n0 + wc + j * 16 + fr;
            const float bv = bias[col];
#pragma unroll
            for (int q = 0; q < 4; ++q) {
                const int row = m0 + wr + i * 16 + r4 + q;
                const float v = acc[i][j][q] + bv;
                if (BF16OUT) ((unsigned short*)Cout)[(size_t)row * N + col] = f2bf(v);
                else         ((float*)Cout)[(size_t)row * N + col] = v;
            }
        }
    }
}

// ---------------------------------------------------------------------------
// rope + repack: qkvb bf16 [B*T][6144] -> Qb,Kb [bh][T][128] (roped), Vt [bh][128][T]
// block = (b, h, 64 t-rows), 256 threads.
// FIX (R3 bug): the non-roped copy (dims 64..127) previously wrote only 32
// elements (dims 64..95), leaving 96..127 stale -> absmax 0.587. Now copies 64.
// ---------------------------------------------------------------------------
__global__ __launch_bounds__(256)
void rope_repack(const unsigned short* __restrict__ qkvb, const float* __restrict__ cosb,
                 const float* __restrict__ sinb, unsigned short* __restrict__ Qb,
                 unsigned short* __restrict__ Kb, unsigned short* __restrict__ Vt) {
    __shared__ unsigned short Vlds[64 * 132];

    const int tid = threadIdx.x;
    const int t64 = blockIdx.x & 31;
    const int h   = (blockIdx.x >> 5) & 15;
    const int b   = blockIdx.x >> 9;
    const int bh  = b * NHEAD + h;
    const int t0  = t64 * 64;

    const int r = tid >> 2, part = tid & 3;
    const size_t inrow  = ((size_t)(b * T_DIM + t0 + r)) * QKV_N + h * 384;
    const size_t outrow = ((size_t)bh * T_DIM + t0 + r) * HS;

    {   // q/k: part 0 = q-rope, 1 = q-copy, 2 = k-rope, 3 = k-copy
        const int isK = part >> 1;
        const int sub = part & 1;
        const unsigned short* src = qkvb + inrow + isK * 128;
        unsigned short* dst = (isK ? Kb : Qb) + outrow;
        if (sub == 0) {
#pragma unroll
            for (int g = 0; g < 8; ++g) {
                const int i = g * 4;
                ushort4 t1 = *(const ushort4*)&src[i];
                ushort4 t2 = *(const ushort4*)&src[32 + i];
                const float4 cv = *(const float4*)&cosb[(t0 + r) * 64 + i];
                const float4 sv = *(const float4*)&sinb[(t0 + r) * 64 + i];
                const float a0 = bf2f(t1.x), a1 = bf2f(t1.y), a2 = bf2f(t1.z), a3 = bf2f(t1.w);
                const float b0 = bf2f(t2.x), b1 = bf2f(t2.y), b2 = bf2f(t2.z), b3 = bf2f(t2.w);
                *(ushort4*)&dst[i] = make_ushort4(
                    f2bf(a0 * cv.x - b0 * sv.x), f2bf(a1 * cv.y - b1 * sv.y),
                    f2bf(a2 * cv.z - b2 * sv.z), f2bf(a3 * cv.w - b3 * sv.w));
                *(ushort4*)&dst[32 + i] = make_ushort4(
                    f2bf(b0 * cv.x + a0 * sv.x), f2bf(b1 * cv.y + a1 * sv.y),
                    f2bf(b2 * cv.z + a2 * sv.z), f2bf(b3 * cv.w + a3 * sv.w));
            }
        } else {
#pragma unroll
            for (int g = 0; g < 8; ++g) {   // FIX: 8 x 8 elems = dims 64..127
                *(ushort4*)&dst[64 + g * 8]     = *(const ushort4*)&src[64 + g * 8];
                *(ushort4*)&dst[64 + g * 8 + 4] = *(const ushort4*)&src[64 + g * 8 + 4];
            }
        }
    }

    {   // V transpose through LDS
        const unsigned short* vsrc = qkvb + inrow + 256;
#pragma unroll
        for (int g = 0; g < 8; ++g)
            *(ushort4*)&Vlds[r * 132 + part * 32 + g * 4] = *(const ushort4*)&vsrc[part * 32 + g * 4];
    }
    __syncthreads();
    {
        const int d = tid >> 1, tc = tid & 1;
        unsigned short* vdst = Vt + ((size_t)bh * HS + d) * T_DIM + t0 + tc * 32;
#pragma unroll
        for (int g = 0; g < 8; ++g) {
            ushort4 o;
            o.x = Vlds[(tc * 32 + g * 4 + 0) * 132 + d];
            o.y = Vlds[(tc * 32 + g * 4 + 1) * 132 + d];
            o.z = Vlds[(tc * 32 + g * 4 + 2) * 132 + d];
            o.w = Vlds[(tc * 32 + g * 4 + 3) * 132 + d];
            *(ushort4*)&vdst[g * 4] = o;
        }
    }
}

// ---------------------------------------------------------------------------
// adapter qkv (tiny fp32 GEMM, verified R1/R2)
// ---------------------------------------------------------------------------
__global__ __launch_bounds__(64)
void adapter_qkv_kernel(const float* __restrict__ wte, const float* __restrict__ w,
                        const float* __restrict__ bias, float* __restrict__ aqkv) {
    const int n = blockIdx.x;
    const int lane = threadIdx.x;
    float acc[AT];
#pragma unroll
    for (int a = 0; a < AT; ++a) acc[a] = 0.f;
    for (int k = lane * 4; k < C_DIM; k += 64 * 4) {
        float4 wv = *(const float4*)&w[(size_t)n * C_DIM + k];
#pragma unroll
        for (int a = 0; a < AT; ++a) {
            float4 tv = *(const float4*)&wte[(size_t)a * C_DIM + k];
            acc[a] += wv.x * tv.x + wv.y * tv.y + wv.z * tv.z + wv.w * tv.w;
        }
    }
#pragma unroll
    for (int a = 0; a < AT; ++a) {
        float v = acc[a];
        for (int off = 32; off; off >>= 1) v += __shfl_down(v, off);
        if (lane == 0) aqkv[(size_t)a * QKV_N + n] = v + bias[n];
    }
}

// ---------------------------------------------------------------------------
// MFMA flash causal attention + fused adapter attention.
// 4 waves, q-tile 64 (16 q-rows/wave), k-tile 64.
// Swapped QK^T: S^T = mfma(K_frag, Q_frag) -> lane owns q-row (lane&15);
// softmax reduce = shfl_xor 16,32. P redistributed in-register (cvt_pk + shfls)
// into the PV A-fragment. K/Vt staged with both-sides XOR swizzle (rule #21).
// FIX (latent): adapter k/v use the reference's BLOCKED split layout
// (ak = aqkv[:, C + h*HS], av = aqkv[:, 2C + h*HS]), not the interleaved one.
// ---------------------------------------------------------------------------
__global__ __launch_bounds__(256)
void flash_mfma(const unsigned short* __restrict__ Qb, const unsigned short* __restrict__ Kb,
                const unsigned short* __restrict__ Vt, const float* __restrict__ aqkv,
                const float* __restrict__ gating, unsigned short* __restrict__ yb) {
    __shared__ __align__(16) unsigned char smem[32768];
    unsigned short* Ks = (unsigned short*)smem;             // [64][128] bf16, 256B rows, swizzled
    unsigned short* Vs = (unsigned short*)(smem + 16384);   // [128][64] bf16, 128B rows, swizzled

    const int tid = threadIdx.x;
    const int wave = tid >> 6, lane = tid & 63;
    const int lo = lane & 15, hi = lane >> 4;

    const int qt = 31 - (blockIdx.x & 31);     // heavy blocks first
    const int h  = (blockIdx.x >> 5) & 15;
    const int b  = blockIdx.x >> 9;
    const int q0 = qt * 64;
    const int bh = b * NHEAD + h;
    const float scale = 0.08838834764831845f;  // 1/sqrt(128)

    const unsigned short* Qh = Qb + (size_t)bh * T_DIM * HS;
    const unsigned short* Kh = Kb + (size_t)bh * T_DIM * HS;
    const unsigned short* Vh = Vt + (size_t)bh * HS * T_DIM;

    const int myqrow = q0 + wave * 16 + lo;

    // Q fragments straight from global (once per block)
    bf16x8 qf[4];
    {
        const unsigned short* qrow = Qh + (size_t)myqrow * HS;
#pragma unroll
        for (int c = 0; c < 4; ++c) qf[c] = *(const bf16x8*)&qrow[c * 32 + hi * 8];
    }

    f32x4v oacc[8];
#pragma unroll
    for (int d = 0; d < 8; ++d)
#pragma unroll
        for (int q = 0; q < 4; ++q) oacc[d][q] = 0.f;
    float m = -INFINITY, ln = 0.f;

    const int ntiles = qt + 1;
    for (int kt = 0; kt < ntiles; ++kt) {
        const int k0 = kt * 64;
        __syncthreads();
        // stage K (64x128, 256B rows) and Vt (128x64, 128B rows), pre-swizzled source
#pragma unroll
        for (int t = 0; t < 4; ++t) {
            const int kr = wave * 16 + t * 4 + hi;               // K row this lane feeds
            gload_lds16(Kh + (size_t)(k0 + kr) * HS + 8 * (lo ^ (kr & 7)),
                        &Ks[(wave * 16 + t * 4) * 128]);
            const int vr = (wave * 4 + t) * 8 + (lane >> 3);     // Vt row this lane feeds
            gload_lds16(Vh + (size_t)vr * T_DIM + k0 + 8 * ((lane & 7) ^ (vr & 7)),
                        &Vs[(wave * 4 + t) * 8 * 64]);
        }
        __syncthreads();

        // ---- S^T = K x Q^T : 16 MFMAs ----
        f32x4v sacc[4];
#pragma unroll
        for (int s = 0; s < 4; ++s) {
#pragma unroll
            for (int q = 0; q < 4; ++q) sacc[s][q] = 0.f;
            const int krow = s * 16 + lo;
            const int rs = (lo & 7) << 4;
#pragma unroll
            for (int c = 0; c < 4; ++c) {
                const int boff = (c * 64 + hi * 16) ^ rs;
                bf16x8 kf = *(const bf16x8*)&Ks[krow * 128 + (boff >> 1)];
                sacc[s] = __builtin_amdgcn_mfma_f32_16x16x32_bf16(kf, qf[c], sacc[s], 0, 0, 0);
            }
        }

        // ---- online softmax (lane owns q-row lo; keys = s*16 + hi*4 + q) ----
        const bool dtile = (kt == qt);
        float p[4][4];
        float xm = -INFINITY;
#pragma unroll
        for (int s = 0; s < 4; ++s)
#pragma unroll
            for (int q = 0; q < 4; ++q) {
                float v = sacc[s][q] * scale;
                if (dtile && (k0 + s * 16 + hi * 4 + q > myqrow)) v = -INFINITY;
                p[s][q] = v;
                xm = fmaxf(xm, v);
            }
        xm = fmaxf(xm, __shfl_xor(xm, 16));
        xm = fmaxf(xm, __shfl_xor(xm, 32));
        const float mnew = fmaxf(m, xm);
        const float al = __expf(m - mnew);
        float psum = 0.f;
#pragma unroll
        for (int s = 0; s < 4; ++s)
#pragma unroll
            for (int q = 0; q < 4; ++q) {
                p[s][q] = __expf(p[s][q] - mnew);
                psum += p[s][q];
            }
        psum += __shfl_xor(psum, 16);
        psum += __shfl_xor(psum, 32);
        ln = ln * al + psum;
        m = mnew;

        // rescale O (O rows are hi*4+q; alpha lives at lane==row)
        float aq[4];
#pragma unroll
        for (int q = 0; q < 4; ++q) aq[q] = __shfl(al, hi * 4 + q);
#pragma unroll
        for (int d = 0; d < 8; ++d)
#pragma unroll
            for (int q = 0; q < 4; ++q) oacc[d][q] *= aq[q];

        // ---- P -> bf16 A-fragments (in-register redistribution) ----
        unsigned int pk[4][2];
#pragma unroll
        for (int s = 0; s < 4; ++s) {
            pk[s][0] = pack_bf16(p[s][0], p[s][1]);
            pk[s][1] = pack_bf16(p[s][2], p[s][3]);
        }
        const int src0 = lo + ((hi & 1) << 5);   // lane holding key-part hp0=(hi&1)*2
        const int src1 = src0 + 16;              // hp1
        const bool shi = (hi >> 1) != 0;
#pragma unroll
        for (int c = 0; c < 2; ++c) {
            const unsigned int a0 = (unsigned int)__shfl((int)pk[c*2][0], src0);
            const unsigned int b0 = (unsigned int)__shfl((int)pk[c*2+1][0], src0);
            const unsigned int a1 = (unsigned int)__shfl((int)pk[c*2][1], src0);
            const unsigned int b1 = (unsigned int)__shfl((int)pk[c*2+1][1], src0);
            const unsigned int a2 = (unsigned int)__shfl((int)pk[c*2][0], src1);
            const unsigned int b2 = (unsigned int)__shfl((int)pk[c*2+1][0], src1);
            const unsigned int a3 = (unsigned int)__shfl((int)pk[c*2][1], src1);
            const unsigned int b3 = (unsigned int)__shfl((int)pk[c*2+1][1], src1);
            union { unsigned int u[4]; bf16x8 v; } cv2;
            cv2.u[0] = shi ? b0 : a0;
            cv2.u[1] = shi ? b1 : a1;
            cv2.u[2] = shi ? b2 : a2;
            cv2.u[3] = shi ? b3 : a3;
            const bf16x8 pf = cv2.v;
            // ---- PV: 8 MFMAs per key-chunk ----
#pragma unroll
            for (int d = 0; d < 8; ++d) {
                const int vrow = d * 16 + lo;
                const int boff = (c * 64 + hi * 16) ^ ((lo & 7) << 4);
                bf16x8 vf = *(const bf16x8*)&Vs[vrow * 64 + (boff >> 1)];
                oacc[d] = __builtin_amdgcn_mfma_f32_16x16x32_bf16(pf, vf, oacc[d], 0, 0, 0);
            }
        }
    }

    // normalize (1/l per O-row)
    float linv[4];
#pragma unroll
    for (int q = 0; q < 4; ++q) linv[q] = 1.f / __shfl(ln, hi * 4 + q);
#pragma unroll
    for (int d = 0; d < 8; ++d)
#pragma unroll
        for (int q = 0; q < 4; ++q) oacc[d][q] *= linv[q];

    // ---- adapter attention (10 keys, unmasked; BLOCKED aqkv layout) ----
    __syncthreads();
    float* AK = (float*)smem;          // [10][128]
    float* AV = AK + AT * HS;
    for (int idx = tid; idx < AT * HS; idx += 256) {
        const int a = idx >> 7, d = idx & 127;
        AK[idx] = aqkv[(size_t)a * QKV_N + C_DIM + h * HS + d];
        AV[idx] = aqkv[(size_t)a * QKV_N + 2 * C_DIM + h * HS + d];
    }
    __syncthreads();

    float qflt[4][8];
#pragma unroll
    for (int c = 0; c < 4; ++c)
#pragma unroll
        for (int j = 0; j < 8; ++j) qflt[c][j] = bf2f((unsigned short)qf[c][j]);

    float e[AT];
    float amax = -INFINITY;
#pragma unroll
    for (int a = 0; a < AT; ++a) {
        float t = 0.f;
#pragma unroll
        for (int c = 0; c < 4; ++c) {
            const float4 k0v = *(const float4*)&AK[a * HS + c * 32 + hi * 8];
            const float4 k1v = *(const float4*)&AK[a * HS + c * 32 + hi * 8 + 4];
            t += qflt[c][0] * k0v.x + qflt[c][1] * k0v.y + qflt[c][2] * k0v.z + qflt[c][3] * k0v.w
               + qflt[c][4] * k1v.x + qflt[c][5] * k1v.y + qflt[c][6] * k1v.z + qflt[c][7] * k1v.w;
        }
        t += __shfl_xor(t, 16);
        t += __shfl_xor(t, 32);
        e[a] = t * scale;
        amax = fmaxf(amax, e[a]);
    }
    float asum = 0.f;
#pragma unroll
    for (int a = 0; a < AT; ++a) { e[a] = __expf(e[a] - amax); asum += e[a]; }
    const float gcoef = gating[0] / asum;

#pragma unroll
    for (int a = 0; a < AT; ++a) {
        const float ca = e[a] * gcoef;
        float cq[4];
#pragma unroll
        for (int q = 0; q < 4; ++q) cq[q] = __shfl(ca, hi * 4 + q);
#pragma unroll
        for (int d = 0; d < 8; ++d) {
            const float av = AV[a * HS + d * 16 + lo];
#pragma unroll
            for (int q = 0; q < 4; ++q) oacc[d][q] += cq[q] * av;
        }
    }

    // write y bf16, (B,T,C) layout
#pragma unroll
    for (int q = 0; q < 4; ++q) {
        const int row = q0 + wave * 16 + hi * 4 + q;
        unsigned short* dst = yb + ((size_t)(b * T_DIM + row)) * C_DIM + h * HS + lo;
#pragma unroll
        for (int d = 0; d < 8; ++d) dst[d * 16] = f2bf(oacc[d][q]);
    }
}

// ---------------------------------------------------------------------------
extern "C" void kernel_launch(void* const* d_in, const int* in_sizes, int n_in,
                              void* d_out, int out_size, void* d_ws, size_t ws_size,
                              hipStream_t stream) {
    const float* x       = (const float*)d_in[0];
    const float* cosb    = (const float*)d_in[1];
    const float* sinb    = (const float*)d_in[2];
    // d_in[3] = mask (causal, unused)
    const float* attn_w  = (const float*)d_in[4];
    const float* attn_b  = (const float*)d_in[5];
    const float* proj_w  = (const float*)d_in[6];
    const float* proj_b  = (const float*)d_in[7];
    const float* wte     = (const float*)d_in[8];
    const float* gating  = (const float*)d_in[9];
    float* out = (float*)d_out;

    // workspace (109.4 MB):
    //   aqkv  f32  [10*6144]                           0.25 MB
    //   qkvb  bf16 [4096*6144]  (later: pwb + yv)     50.33 MB
    //   xb    bf16 [4096*2048]  (later: Qb)           16.78 MB
    //   awb   bf16 [6144*2048]  (later: Kb)           25.17 MB
    //   Vt    bf16 [32*128*2048]                      16.78 MB
    float* aqkv = (float*)d_ws;
    unsigned short* qkvb = (unsigned short*)(aqkv + (size_t)AT * QKV_N);
    unsigned short* xb   = qkvb + (size_t)M_DIM * QKV_N;
    unsigned short* awb  = xb + (size_t)M_DIM * C_DIM;
    unsigned short* Vt   = awb + (size_t)QKV_N * C_DIM;
    unsigned short* Qb   = xb;                                    // alive after gemm1
    unsigned short* Kb   = awb;                                   // alive after gemm1
    unsigned short* pwb  = qkvb;                                  // alive after repack
    unsigned short* yv   = qkvb + (size_t)C_DIM * C_DIM;          // alive after repack

    // 1. convert x, attn_w to bf16
    f32_to_bf16_kernel<<<(M_DIM * C_DIM / 8 + 255) / 256, 256, 0, stream>>>(x, xb, M_DIM * C_DIM / 8);
    f32_to_bf16_kernel<<<(QKV_N * C_DIM / 8 + 255) / 256, 256, 0, stream>>>(attn_w, awb, QKV_N * C_DIM / 8);
    // 2. qkvb = x @ attn_w^T + attn_b  (bf16 out)
    gemm_nt_mfma<1><<<dim3(QKV_N / 128, M_DIM / 128), 256, 0, stream>>>(
        xb, awb, attn_b, qkvb, M_DIM, QKV_N, C_DIM);
    // 3. adapter qkv (fp32)
    adapter_qkv_kernel<<<QKV_N, 64, 0, stream>>>(wte, attn_w, attn_b, aqkv);
    // 4. rope + repack to Qb/Kb/Vt
    rope_repack<<<B_DIM * NHEAD * (T_DIM / 64), 256, 0, stream>>>(qkvb, cosb, sinb, Qb, Kb, Vt);
    // 5. convert proj_w (into dead qkvb region)
    f32_to_bf16_kernel<<<(C_DIM * C_DIM / 8 + 255) / 256, 256, 0, stream>>>(proj_w, pwb, C_DIM * C_DIM / 8);
    // 6. MFMA flash attention + adapter + gating -> yv (bf16)
    flash_mfma<<<B_DIM * NHEAD * (T_DIM / 64), 256, 0, stream>>>(Qb, Kb, Vt, aqkv, gating, yv);
    // 7. out = y @ proj_w^T + proj_b (f32 out)
    gemm_nt_mfma<0><<<dim3(C_DIM / 128, M_DIM / 128), 256, 0, stream>>>(
        yv, pwb, proj_b, out, M_DIM, C_DIM, C_DIM);
}

// Round 5
// 490.652 us; speedup vs baseline: 7.2204x; 1.0825x over previous
//
#include <hip/hip_runtime.h>
#include <math.h>

// Problem constants (B=2, T=2048, C=2048, NH=16, HS=128, N_ELEM=64, A_T=10)
#define B_DIM 2
#define T_DIM 2048
#define C_DIM 2048
#define NHEAD 16
#define HS 128
#define QKV_N 6144          // 3*C
#define AT 10
#define M_DIM 4096          // B*T

using bf16x8 = __attribute__((ext_vector_type(8))) short;
using f32x4v = __attribute__((ext_vector_type(4))) float;

__device__ __forceinline__ unsigned short f2bf(float f) {
    union { float f; unsigned int u; } cv; cv.f = f;
    unsigned int u = cv.u;
    return (unsigned short)((u + 0x7FFFu + ((u >> 16) & 1u)) >> 16);
}
__device__ __forceinline__ float bf2f(unsigned short h) {
    union { unsigned int u; float f; } cv; cv.u = ((unsigned int)h) << 16;
    return cv.f;
}
__device__ __forceinline__ unsigned int pack_bf16(float lo, float hi) {
    unsigned int r;
    asm volatile("v_cvt_pk_bf16_f32 %0, %1, %2" : "=v"(r) : "v"(lo), "v"(hi));
    return r;
}
__device__ __forceinline__ void gload_lds16(const void* g, void* l) {
    __builtin_amdgcn_global_load_lds(
        (const __attribute__((address_space(1))) void*)g,
        (__attribute__((address_space(3))) void*)l, 16, 0, 0);
}

// ---------------------------------------------------------------------------
// f32 -> bf16 convert (8 elems/thread)
// ---------------------------------------------------------------------------
__global__ __launch_bounds__(256)
void f32_to_bf16_kernel(const float* __restrict__ in, unsigned short* __restrict__ out, int n8) {
    const int i = blockIdx.x * 256 + threadIdx.x;
    if (i >= n8) return;
    const float4 a = *(const float4*)&in[(size_t)i * 8];
    const float4 b = *(const float4*)&in[(size_t)i * 8 + 4];
    *(ushort4*)&out[(size_t)i * 8]     = make_ushort4(f2bf(a.x), f2bf(a.y), f2bf(a.z), f2bf(a.w));
    *(ushort4*)&out[(size_t)i * 8 + 4] = make_ushort4(f2bf(b.x), f2bf(b.y), f2bf(b.z), f2bf(b.w));
}

// ---------------------------------------------------------------------------
// bf16 MFMA GEMM NT: C[M][N] = A[M][K]*B[N][K]^T + bias[N]. Out f32 or bf16.
// m97 structure (verified R2/R4) + XCD-aware block swizzle (nwg % 8 == 0).
// ---------------------------------------------------------------------------
template<int BF16OUT>
__global__ __launch_bounds__(256)
void gemm_nt_mfma(const unsigned short* __restrict__ A, const unsigned short* __restrict__ Bw,
                  const float* __restrict__ bias, void* __restrict__ Cout,
                  int M, int N, int K) {
    __shared__ unsigned short As[128 * 32];
    __shared__ unsigned short Bs[128 * 32];

    const int tid  = threadIdx.x;
    const int wave = tid >> 6;
    const int lane = tid & 63;

    // XCD swizzle: consecutive work-chunks land on one XCD's L2 (launch grids
    // are 1536 and 512 blocks, both % 8 == 0 -> simple form is bijective).
    const int nwg = gridDim.x * gridDim.y;
    int bid = blockIdx.y * gridDim.x + blockIdx.x;
    bid = (bid & 7) * (nwg >> 3) + (bid >> 3);
    const int m0 = (bid / gridDim.x) * 128;
    const int n0 = (bid % gridDim.x) * 128;

    const int wr = (wave >> 1) * 64;
    const int wc = (wave & 1) * 64;

    f32x4v acc[4][4];
#pragma unroll
    for (int i = 0; i < 4; ++i)
#pragma unroll
        for (int j = 0; j < 4; ++j)
#pragma unroll
            for (int q = 0; q < 4; ++q) acc[i][j][q] = 0.f;

    const int srow = lane >> 2;
    const int sk   = (lane & 3) * 8;
    const int fr   = lane & 15;
    const int fk   = (lane >> 4) * 8;

    for (int k0 = 0; k0 < K; k0 += 32) {
        __syncthreads();
#pragma unroll
        for (int t = 0; t < 2; ++t) {
            const int seg = wave * 2 + t;
            gload_lds16(&A[(size_t)(m0 + seg * 16 + srow) * K + k0 + sk], &As[seg * 512]);
            gload_lds16(&Bw[(size_t)(n0 + seg * 16 + srow) * K + k0 + sk], &Bs[seg * 512]);
        }
        __syncthreads();

        bf16x8 af[4], bfg[4];
#pragma unroll
        for (int i = 0; i < 4; ++i)
            af[i] = *(const bf16x8*)&As[(wr + i * 16 + fr) * 32 + fk];
#pragma unroll
        for (int j = 0; j < 4; ++j)
            bfg[j] = *(const bf16x8*)&Bs[(wc + j * 16 + fr) * 32 + fk];
#pragma unroll
        for (int i = 0; i < 4; ++i)
#pragma unroll
            for (int j = 0; j < 4; ++j)
                acc[i][j] = __builtin_amdgcn_mfma_f32_16x16x32_bf16(af[i], bfg[j], acc[i][j], 0, 0, 0);
    }

    const int r4 = (lane >> 4) * 4;
#pragma unroll
    for (int i = 0; i < 4; ++i) {
#pragma unroll
        for (int j = 0; j < 4; ++j) {
            const int col = n0 + wc + j * 16 + fr;
            const float bv = bias[col];
#pragma unroll
            for (int q = 0; q < 4; ++q) {
                const int row = m0 + wr + i * 16 + r4 + q;
                const float v = acc[i][j][q] + bv;
                if (BF16OUT) ((unsigned short*)Cout)[(size_t)row * N + col] = f2bf(v);
                else         ((float*)Cout)[(size_t)row * N + col] = v;
            }
        }
    }
}

// ---------------------------------------------------------------------------
// rope + repack (verified R4): qkvb bf16 -> Qb,Kb [bh][T][128] roped, Vt [bh][128][T]
// ---------------------------------------------------------------------------
__global__ __launch_bounds__(256)
void rope_repack(const unsigned short* __restrict__ qkvb, const float* __restrict__ cosb,
                 const float* __restrict__ sinb, unsigned short* __restrict__ Qb,
                 unsigned short* __restrict__ Kb, unsigned short* __restrict__ Vt) {
    __shared__ unsigned short Vlds[64 * 132];

    const int tid = threadIdx.x;
    const int t64 = blockIdx.x & 31;
    const int h   = (blockIdx.x >> 5) & 15;
    const int b   = blockIdx.x >> 9;
    const int bh  = b * NHEAD + h;
    const int t0  = t64 * 64;

    const int r = tid >> 2, part = tid & 3;
    const size_t inrow  = ((size_t)(b * T_DIM + t0 + r)) * QKV_N + h * 384;
    const size_t outrow = ((size_t)bh * T_DIM + t0 + r) * HS;

    {   // q/k: part 0 = q-rope, 1 = q-copy, 2 = k-rope, 3 = k-copy
        const int isK = part >> 1;
        const int sub = part & 1;
        const unsigned short* src = qkvb + inrow + isK * 128;
        unsigned short* dst = (isK ? Kb : Qb) + outrow;
        if (sub == 0) {
#pragma unroll
            for (int g = 0; g < 8; ++g) {
                const int i = g * 4;
                ushort4 t1 = *(const ushort4*)&src[i];
                ushort4 t2 = *(const ushort4*)&src[32 + i];
                const float4 cv = *(const float4*)&cosb[(t0 + r) * 64 + i];
                const float4 sv = *(const float4*)&sinb[(t0 + r) * 64 + i];
                const float a0 = bf2f(t1.x), a1 = bf2f(t1.y), a2 = bf2f(t1.z), a3 = bf2f(t1.w);
                const float b0 = bf2f(t2.x), b1 = bf2f(t2.y), b2 = bf2f(t2.z), b3 = bf2f(t2.w);
                *(ushort4*)&dst[i] = make_ushort4(
                    f2bf(a0 * cv.x - b0 * sv.x), f2bf(a1 * cv.y - b1 * sv.y),
                    f2bf(a2 * cv.z - b2 * sv.z), f2bf(a3 * cv.w - b3 * sv.w));
                *(ushort4*)&dst[32 + i] = make_ushort4(
                    f2bf(b0 * cv.x + a0 * sv.x), f2bf(b1 * cv.y + a1 * sv.y),
                    f2bf(b2 * cv.z + a2 * sv.z), f2bf(b3 * cv.w + a3 * sv.w));
            }
        } else {
#pragma unroll
            for (int g = 0; g < 8; ++g) {   // dims 64..127 (R4 fix)
                *(ushort4*)&dst[64 + g * 8]     = *(const ushort4*)&src[64 + g * 8];
                *(ushort4*)&dst[64 + g * 8 + 4] = *(const ushort4*)&src[64 + g * 8 + 4];
            }
        }
    }

    {   // V transpose through LDS
        const unsigned short* vsrc = qkvb + inrow + 256;
#pragma unroll
        for (int g = 0; g < 8; ++g)
            *(ushort4*)&Vlds[r * 132 + part * 32 + g * 4] = *(const ushort4*)&vsrc[part * 32 + g * 4];
    }
    __syncthreads();
    {
        const int d = tid >> 1, tc = tid & 1;
        unsigned short* vdst = Vt + ((size_t)bh * HS + d) * T_DIM + t0 + tc * 32;
#pragma unroll
        for (int g = 0; g < 8; ++g) {
            ushort4 o;
            o.x = Vlds[(tc * 32 + g * 4 + 0) * 132 + d];
            o.y = Vlds[(tc * 32 + g * 4 + 1) * 132 + d];
            o.z = Vlds[(tc * 32 + g * 4 + 2) * 132 + d];
            o.w = Vlds[(tc * 32 + g * 4 + 3) * 132 + d];
            *(ushort4*)&vdst[g * 4] = o;
        }
    }
}

// ---------------------------------------------------------------------------
// adapter qkv (tiny GEMM) — now reads bf16 weights (half the traffic)
// ---------------------------------------------------------------------------
__global__ __launch_bounds__(64)
void adapter_qkv_kernel(const float* __restrict__ wte, const unsigned short* __restrict__ wb,
                        const float* __restrict__ bias, float* __restrict__ aqkv) {
    const int n = blockIdx.x;
    const int lane = threadIdx.x;
    float acc[AT];
#pragma unroll
    for (int a = 0; a < AT; ++a) acc[a] = 0.f;
    for (int k = lane * 8; k < C_DIM; k += 64 * 8) {
        const ushort4 wa = *(const ushort4*)&wb[(size_t)n * C_DIM + k];
        const ushort4 wc = *(const ushort4*)&wb[(size_t)n * C_DIM + k + 4];
        const float w0 = bf2f(wa.x), w1 = bf2f(wa.y), w2 = bf2f(wa.z), w3 = bf2f(wa.w);
        const float w4 = bf2f(wc.x), w5 = bf2f(wc.y), w6 = bf2f(wc.z), w7 = bf2f(wc.w);
#pragma unroll
        for (int a = 0; a < AT; ++a) {
            const float4 t0 = *(const float4*)&wte[(size_t)a * C_DIM + k];
            const float4 t1 = *(const float4*)&wte[(size_t)a * C_DIM + k + 4];
            acc[a] += w0 * t0.x + w1 * t0.y + w2 * t0.z + w3 * t0.w
                    + w4 * t1.x + w5 * t1.y + w6 * t1.z + w7 * t1.w;
        }
    }
#pragma unroll
    for (int a = 0; a < AT; ++a) {
        float v = acc[a];
        for (int off = 32; off; off >>= 1) v += __shfl_down(v, off);
        if (lane == 0) aqkv[(size_t)a * QKV_N + n] = v + bias[n];
    }
}

// ---------------------------------------------------------------------------
// MFMA flash causal attention v2 + fused adapter attention.
// Changes vs R4 (verified math kept identical):
//  - qt-pairing: block (b,h,z) runs q-tiles 31-z and z -> all blocks = 33 tiles.
//  - double-buffered K/V staging, ONE __syncthreads per k-tile; next tile's
//    global_load_lds issued before compute -> latency hidden under compute.
//  - softmax in log2 domain (exp2), defer-max (skip rescale unless growth>11.5),
//    s_setprio(1) around MFMA clusters.
// LDS = 64 KB (2 x (K 16KB + V 16KB)); adapter K/V overlays buf0 post-loop.
// ---------------------------------------------------------------------------
__global__ __launch_bounds__(256)
void flash_mfma(const unsigned short* __restrict__ Qb, const unsigned short* __restrict__ Kb,
                const unsigned short* __restrict__ Vt, const float* __restrict__ aqkv,
                const float* __restrict__ gating, unsigned short* __restrict__ yb) {
    __shared__ __align__(16) unsigned short smem[2][16384];   // [buf][K:8192 | V:8192]

    const int tid = threadIdx.x;
    const int wave = tid >> 6, lane = tid & 63;
    const int lo = lane & 15, hi = lane >> 4;

    const int z = blockIdx.x & 15;
    const int h = (blockIdx.x >> 4) & 15;
    const int b = blockIdx.x >> 8;
    const int bh = b * NHEAD + h;
    const float kscale = 0.08838834764831845f * 1.4426950408889634f;  // scale*log2(e)

    const unsigned short* Qh = Qb + (size_t)bh * T_DIM * HS;
    const unsigned short* Kh = Kb + (size_t)bh * T_DIM * HS;
    const unsigned short* Vh = Vt + (size_t)bh * HS * T_DIM;

    float* AK = (float*)&smem[0][0];     // adapter overlay (10x128 f32 x2 = 10KB)
    float* AV = AK + AT * HS;

    auto STAGE = [&](int k0, int bufi) {
        unsigned short* Kd = &smem[bufi][0];
        unsigned short* Vd = &smem[bufi][8192];
#pragma unroll
        for (int t = 0; t < 4; ++t) {
            const int kr = wave * 16 + t * 4 + hi;
            gload_lds16(Kh + (size_t)(k0 + kr) * HS + 8 * (lo ^ (kr & 7)),
                        &Kd[(wave * 16 + t * 4) * 128]);
            const int vr = (wave * 4 + t) * 8 + (lane >> 3);
            gload_lds16(Vh + (size_t)vr * T_DIM + k0 + 8 * ((lane & 7) ^ (vr & 7)),
                        &Vd[(wave * 4 + t) * 8 * 64]);
        }
    };

#pragma unroll 1
    for (int pass = 0; pass < 2; ++pass) {
        const int qt = pass ? z : (31 - z);
        const int q0 = qt * 64;
        const int myqrow = q0 + wave * 16 + lo;

        // Q fragments from global
        bf16x8 qf[4];
        {
            const unsigned short* qrow = Qh + (size_t)myqrow * HS;
#pragma unroll
            for (int c = 0; c < 4; ++c) qf[c] = *(const bf16x8*)&qrow[c * 32 + hi * 8];
        }

        f32x4v oacc[8];
#pragma unroll
        for (int d = 0; d < 8; ++d)
#pragma unroll
            for (int q = 0; q < 4; ++q) oacc[d][q] = 0.f;
        float m = -INFINITY, ln = 0.f;

        STAGE(0, 0);
        int cur = 0;
        for (int kt = 0; kt <= qt; ++kt) {
            const int k0 = kt * 64;
            __syncthreads();                      // drains vmcnt: buf[cur] ready; prev compute done
            if (kt < qt) STAGE(k0 + 64, cur ^ 1); // prefetch next tile under this compute
            const unsigned short* Ks = &smem[cur][0];
            const unsigned short* Vs = &smem[cur][8192];

            // ---- S^T = K x Q^T : 16 MFMAs ----
            f32x4v sacc[4];
            __builtin_amdgcn_s_setprio(1);
#pragma unroll
            for (int s = 0; s < 4; ++s) {
#pragma unroll
                for (int q = 0; q < 4; ++q) sacc[s][q] = 0.f;
                const int krow = s * 16 + lo;
                const int rs = (lo & 7) << 4;
#pragma unroll
                for (int c = 0; c < 4; ++c) {
                    const int boff = (c * 64 + hi * 16) ^ rs;
                    bf16x8 kf = *(const bf16x8*)&Ks[krow * 128 + (boff >> 1)];
                    sacc[s] = __builtin_amdgcn_mfma_f32_16x16x32_bf16(kf, qf[c], sacc[s], 0, 0, 0);
                }
            }
            __builtin_amdgcn_s_setprio(0);

            // ---- online softmax, log2 domain (lane owns q-row lo) ----
            const bool dtile = (kt == qt);
            float p[4][4];
            float xm = -INFINITY;
#pragma unroll
            for (int s = 0; s < 4; ++s)
#pragma unroll
                for (int q = 0; q < 4; ++q) {
                    float v = sacc[s][q] * kscale;
                    if (dtile && (k0 + s * 16 + hi * 4 + q > myqrow)) v = -INFINITY;
                    p[s][q] = v;
                    xm = fmaxf(xm, v);
                }
            xm = fmaxf(xm, __shfl_xor(xm, 16));
            xm = fmaxf(xm, __shfl_xor(xm, 32));
            if (__any(xm > m + 11.5f)) {          // defer-max: rescale only on real growth
                const float mnew = fmaxf(m, xm);
                const float al = exp2f(m - mnew);
                m = mnew;
                ln *= al;
                float aq[4];
#pragma unroll
                for (int q = 0; q < 4; ++q) aq[q] = __shfl(al, hi * 4 + q);
#pragma unroll
                for (int d = 0; d < 8; ++d)
#pragma unroll
                    for (int q = 0; q < 4; ++q) oacc[d][q] *= aq[q];
            }
            float psum = 0.f;
#pragma unroll
            for (int s = 0; s < 4; ++s)
#pragma unroll
                for (int q = 0; q < 4; ++q) {
                    p[s][q] = exp2f(p[s][q] - m);
                    psum += p[s][q];
                }
            psum += __shfl_xor(psum, 16);
            psum += __shfl_xor(psum, 32);
            ln += psum;

            // ---- P -> bf16 A-fragments (in-register redistribution) ----
            unsigned int pk[4][2];
#pragma unroll
            for (int s = 0; s < 4; ++s) {
                pk[s][0] = pack_bf16(p[s][0], p[s][1]);
                pk[s][1] = pack_bf16(p[s][2], p[s][3]);
            }
            const int src0 = lo + ((hi & 1) << 5);
            const int src1 = src0 + 16;
            const bool shi = (hi >> 1) != 0;
#pragma unroll
            for (int c = 0; c < 2; ++c) {
                const unsigned int a0 = (unsigned int)__shfl((int)pk[c*2][0], src0);
                const unsigned int b0 = (unsigned int)__shfl((int)pk[c*2+1][0], src0);
                const unsigned int a1 = (unsigned int)__shfl((int)pk[c*2][1], src0);
                const unsigned int b1 = (unsigned int)__shfl((int)pk[c*2+1][1], src0);
                const unsigned int a2 = (unsigned int)__shfl((int)pk[c*2][0], src1);
                const unsigned int b2 = (unsigned int)__shfl((int)pk[c*2+1][0], src1);
                const unsigned int a3 = (unsigned int)__shfl((int)pk[c*2][1], src1);
                const unsigned int b3 = (unsigned int)__shfl((int)pk[c*2+1][1], src1);
                union { unsigned int u[4]; bf16x8 v; } cv2;
                cv2.u[0] = shi ? b0 : a0;
                cv2.u[1] = shi ? b1 : a1;
                cv2.u[2] = shi ? b2 : a2;
                cv2.u[3] = shi ? b3 : a3;
                const bf16x8 pf = cv2.v;
                __builtin_amdgcn_s_setprio(1);
#pragma unroll
                for (int d = 0; d < 8; ++d) {
                    const int vrow = d * 16 + lo;
                    const int boff = (c * 64 + hi * 16) ^ ((lo & 7) << 4);
                    bf16x8 vf = *(const bf16x8*)&Vs[vrow * 64 + (boff >> 1)];
                    oacc[d] = __builtin_amdgcn_mfma_f32_16x16x32_bf16(pf, vf, oacc[d], 0, 0, 0);
                }
                __builtin_amdgcn_s_setprio(0);
            }
            cur ^= 1;
        }

        // normalize (1/l per O-row)
        float linv[4];
#pragma unroll
        for (int q = 0; q < 4; ++q) linv[q] = 1.f / __shfl(ln, hi * 4 + q);
#pragma unroll
        for (int d = 0; d < 8; ++d)
#pragma unroll
            for (int q = 0; q < 4; ++q) oacc[d][q] *= linv[q];

        // ---- adapter attention (10 keys, unmasked; BLOCKED aqkv layout) ----
        __syncthreads();                     // all waves done with K/V LDS
        for (int idx = tid; idx < AT * HS; idx += 256) {
            const int a = idx >> 7, d = idx & 127;
            AK[idx] = aqkv[(size_t)a * QKV_N + C_DIM + h * HS + d];
            AV[idx] = aqkv[(size_t)a * QKV_N + 2 * C_DIM + h * HS + d];
        }
        __syncthreads();

        float qflt[4][8];
#pragma unroll
        for (int c = 0; c < 4; ++c)
#pragma unroll
            for (int j = 0; j < 8; ++j) qflt[c][j] = bf2f((unsigned short)qf[c][j]);

        float e[AT];
        float amax = -INFINITY;
#pragma unroll
        for (int a = 0; a < AT; ++a) {
            float t = 0.f;
#pragma unroll
            for (int c = 0; c < 4; ++c) {
                const float4 k0v = *(const float4*)&AK[a * HS + c * 32 + hi * 8];
                const float4 k1v = *(const float4*)&AK[a * HS + c * 32 + hi * 8 + 4];
                t += qflt[c][0] * k0v.x + qflt[c][1] * k0v.y + qflt[c][2] * k0v.z + qflt[c][3] * k0v.w
                   + qflt[c][4] * k1v.x + qflt[c][5] * k1v.y + qflt[c][6] * k1v.z + qflt[c][7] * k1v.w;
            }
            t += __shfl_xor(t, 16);
            t += __shfl_xor(t, 32);
            e[a] = t * 0.08838834764831845f;
            amax = fmaxf(amax, e[a]);
        }
        float asum = 0.f;
#pragma unroll
        for (int a = 0; a < AT; ++a) { e[a] = __expf(e[a] - amax); asum += e[a]; }
        const float gcoef = gating[0] / asum;

#pragma unroll
        for (int a = 0; a < AT; ++a) {
            const float ca = e[a] * gcoef;
            float cq[4];
#pragma unroll
            for (int q = 0; q < 4; ++q) cq[q] = __shfl(ca, hi * 4 + q);
#pragma unroll
            for (int d = 0; d < 8; ++d) {
                const float av = AV[a * HS + d * 16 + lo];
#pragma unroll
                for (int q = 0; q < 4; ++q) oacc[d][q] += cq[q] * av;
            }
        }

        // write y bf16, (B,T,C) layout
#pragma unroll
        for (int q = 0; q < 4; ++q) {
            const int row = q0 + wave * 16 + hi * 4 + q;
            unsigned short* dst = yb + ((size_t)(b * T_DIM + row)) * C_DIM + h * HS + lo;
#pragma unroll
            for (int d = 0; d < 8; ++d) dst[d * 16] = f2bf(oacc[d][q]);
        }

        if (pass == 0) __syncthreads();      // AK/AV reads done before pass1 re-stages buf0
    }
}

// ---------------------------------------------------------------------------
extern "C" void kernel_launch(void* const* d_in, const int* in_sizes, int n_in,
                              void* d_out, int out_size, void* d_ws, size_t ws_size,
                              hipStream_t stream) {
    const float* x       = (const float*)d_in[0];
    const float* cosb    = (const float*)d_in[1];
    const float* sinb    = (const float*)d_in[2];
    // d_in[3] = mask (causal, unused)
    const float* attn_w  = (const float*)d_in[4];
    const float* attn_b  = (const float*)d_in[5];
    const float* proj_w  = (const float*)d_in[6];
    const float* proj_b  = (const float*)d_in[7];
    const float* wte     = (const float*)d_in[8];
    const float* gating  = (const float*)d_in[9];
    float* out = (float*)d_out;

    // workspace (109.4 MB):
    //   aqkv  f32  [10*6144]                           0.25 MB
    //   qkvb  bf16 [4096*6144]  (later: pwb + yv)     50.33 MB
    //   xb    bf16 [4096*2048]  (later: Qb)           16.78 MB
    //   awb   bf16 [6144*2048]  (later: Kb)           25.17 MB
    //   Vt    bf16 [32*128*2048]                      16.78 MB
    float* aqkv = (float*)d_ws;
    unsigned short* qkvb = (unsigned short*)(aqkv + (size_t)AT * QKV_N);
    unsigned short* xb   = qkvb + (size_t)M_DIM * QKV_N;
    unsigned short* awb  = xb + (size_t)M_DIM * C_DIM;
    unsigned short* Vt   = awb + (size_t)QKV_N * C_DIM;
    unsigned short* Qb   = xb;                                    // alive after gemm1
    unsigned short* Kb   = awb;                                   // alive after gemm1
    unsigned short* pwb  = qkvb;                                  // alive after repack
    unsigned short* yv   = qkvb + (size_t)C_DIM * C_DIM;          // alive after repack

    // 1. convert x, attn_w to bf16
    f32_to_bf16_kernel<<<(M_DIM * C_DIM / 8 + 255) / 256, 256, 0, stream>>>(x, xb, M_DIM * C_DIM / 8);
    f32_to_bf16_kernel<<<(QKV_N * C_DIM / 8 + 255) / 256, 256, 0, stream>>>(attn_w, awb, QKV_N * C_DIM / 8);
    // 2. qkvb = x @ attn_w^T + attn_b  (bf16 out)
    gemm_nt_mfma<1><<<dim3(QKV_N / 128, M_DIM / 128), 256, 0, stream>>>(
        xb, awb, attn_b, qkvb, M_DIM, QKV_N, C_DIM);
    // 3. adapter qkv (bf16 weights)
    adapter_qkv_kernel<<<QKV_N, 64, 0, stream>>>(wte, awb, attn_b, aqkv);
    // 4. rope + repack to Qb/Kb/Vt
    rope_repack<<<B_DIM * NHEAD * (T_DIM / 64), 256, 0, stream>>>(qkvb, cosb, sinb, Qb, Kb, Vt);
    // 5. convert proj_w (into dead qkvb region)
    f32_to_bf16_kernel<<<(C_DIM * C_DIM / 8 + 255) / 256, 256, 0, stream>>>(proj_w, pwb, C_DIM * C_DIM / 8);
    // 6. MFMA flash attention + adapter + gating -> yv (bf16); qt-paired blocks
    flash_mfma<<<B_DIM * NHEAD * 16, 256, 0, stream>>>(Qb, Kb, Vt, aqkv, gating, yv);
    // 7. out = y @ proj_w^T + proj_b (f32 out)
    gemm_nt_mfma<0><<<dim3(C_DIM / 128, M_DIM / 128), 256, 0, stream>>>(
        yv, pwb, proj_b, out, M_DIM, C_DIM, C_DIM);
}

// Round 6
// 440.152 us; speedup vs baseline: 8.0488x; 1.1147x over previous
//
#include <hip/hip_runtime.h>
#include <math.h>

// Problem constants (B=2, T=2048, C=2048, NH=16, HS=128, N_ELEM=64, A_T=10)
#define B_DIM 2
#define T_DIM 2048
#define C_DIM 2048
#define NHEAD 16
#define HS 128
#define QKV_N 6144          // 3*C
#define AT 10
#define M_DIM 4096          // B*T

using bf16x8 = __attribute__((ext_vector_type(8))) short;
using f32x4v = __attribute__((ext_vector_type(4))) float;

__device__ __forceinline__ unsigned short f2bf(float f) {
    union { float f; unsigned int u; } cv; cv.f = f;
    unsigned int u = cv.u;
    return (unsigned short)((u + 0x7FFFu + ((u >> 16) & 1u)) >> 16);
}
__device__ __forceinline__ float bf2f(unsigned short h) {
    union { unsigned int u; float f; } cv; cv.u = ((unsigned int)h) << 16;
    return cv.f;
}
__device__ __forceinline__ unsigned int pack_bf16(float lo, float hi) {
    unsigned int r;
    asm volatile("v_cvt_pk_bf16_f32 %0, %1, %2" : "=v"(r) : "v"(lo), "v"(hi));
    return r;
}
__device__ __forceinline__ void gload_lds16(const void* g, void* l) {
    __builtin_amdgcn_global_load_lds(
        (const __attribute__((address_space(1))) void*)g,
        (__attribute__((address_space(3))) void*)l, 16, 0, 0);
}

// ---------------------------------------------------------------------------
// f32 -> bf16 convert (8 elems/thread)
// ---------------------------------------------------------------------------
__global__ __launch_bounds__(256)
void f32_to_bf16_kernel(const float* __restrict__ in, unsigned short* __restrict__ out, int n8) {
    const int i = blockIdx.x * 256 + threadIdx.x;
    if (i >= n8) return;
    const float4 a = *(const float4*)&in[(size_t)i * 8];
    const float4 b = *(const float4*)&in[(size_t)i * 8 + 4];
    *(ushort4*)&out[(size_t)i * 8]     = make_ushort4(f2bf(a.x), f2bf(a.y), f2bf(a.z), f2bf(a.w));
    *(ushort4*)&out[(size_t)i * 8 + 4] = make_ushort4(f2bf(b.x), f2bf(b.y), f2bf(b.z), f2bf(b.w));
}

// ---------------------------------------------------------------------------
// Pipelined bf16 MFMA GEMM NT (R6): C = A[M][K]*B[N][K]^T + bias.
//  - 128x128 tile, BK=32, 4 waves; fragment math verified R2/R4.
//  - 3 LDS buffers, depth-2 prefetch, counted s_waitcnt vmcnt(4) + raw
//    s_barrier (ONE barrier per K-step, loads in flight across barriers).
//  - LDS XOR swizzle (16B granule ^= row&3), both-sides (pre-swizzled global
//    source feeding linear global_load_lds + swizzled ds_read).
//  - grouped (G=8) + XCD-chunked block swizzle for L2 locality.
// FUSED=0: f32 out + bias (proj GEMM).
// FUSED=1: qkv epilogue — bias + RoPE on q/k (d<64) + direct write to
//          Qb/Kb [bh][T][128] and V transposed into Vt [bh][128][T].
//          n-tile maps to exactly one (head, part): 384 = 3*128.
// ---------------------------------------------------------------------------
template<int FUSED>
__global__ __launch_bounds__(256)
void gemm_pipe(const unsigned short* __restrict__ A, const unsigned short* __restrict__ Bw,
               const float* __restrict__ bias, float* __restrict__ Cf32,
               const float* __restrict__ cosb, const float* __restrict__ sinb,
               unsigned short* __restrict__ Qb, unsigned short* __restrict__ Kb,
               unsigned short* __restrict__ Vt, int M, int N, int K) {
    __shared__ unsigned short As[3][4096];   // 3 x 8KB
    __shared__ unsigned short Bs[3][4096];

    const int tid  = threadIdx.x;
    const int wave = tid >> 6;
    const int lane = tid & 63;

    // XCD chunking + grouped (G=8 n-tiles) mapping for L2 locality
    const int ncnt = gridDim.x, mcnt = gridDim.y;
    const int nwg = ncnt * mcnt;
    int bid = blockIdx.y * ncnt + blockIdx.x;
    bid = (bid & 7) * (nwg >> 3) + (bid >> 3);          // per-XCD contiguous chunks
    const int mt = (bid >> 3) % mcnt;
    const int nt = (bid / (mcnt * 8)) * 8 + (bid & 7);  // G=8 column groups
    const int m0 = mt * 128, n0 = nt * 128;

    const int wr = (wave >> 1) * 64;
    const int wc = (wave & 1) * 64;
    const int fr = lane & 15;
    const int hi = lane >> 4;

    // staging: lane covers row seg*16 + (lane>>2), 16B granule (lane&3);
    // source granule pre-swizzled so LDS slot (row,g) holds global g^(row&3)
    const int srow = lane >> 2;
    const int ssk  = 8 * ((lane & 3) ^ ((lane >> 2) & 3));
    // fragment read: k-granule hi at row r -> LDS granule hi^(r&3), r&3 == fr&3
    const int swk  = 8 * (hi ^ (fr & 3));

    auto STAGE = [&](int ks, int bi) {
        const int k0 = ks << 5;
#pragma unroll
        for (int t = 0; t < 2; ++t) {
            const int seg = wave * 2 + t;
            gload_lds16(&A[(size_t)(m0 + seg * 16 + srow) * K + k0 + ssk], &As[bi][seg * 512]);
            gload_lds16(&Bw[(size_t)(n0 + seg * 16 + srow) * K + k0 + ssk], &Bs[bi][seg * 512]);
        }
    };

    f32x4v acc[4][4];
#pragma unroll
    for (int i = 0; i < 4; ++i)
#pragma unroll
        for (int j = 0; j < 4; ++j)
#pragma unroll
            for (int q = 0; q < 4; ++q) acc[i][j][q] = 0.f;

    const int nk = K >> 5;
    STAGE(0, 0);
    STAGE(1, 1);

    for (int ks = 0; ks < nk; ++ks) {
        // wait for buf[ks]'s loads (issued 2 steps ago); keep later stages in flight
        if (ks < nk - 1) asm volatile("s_waitcnt vmcnt(4)" ::: "memory");
        else             asm volatile("s_waitcnt vmcnt(0)" ::: "memory");
        __builtin_amdgcn_sched_barrier(0);
        __builtin_amdgcn_s_barrier();            // all waves' buf[ks] loads done;
        asm volatile("" ::: "memory");           //  buf[ks-1] readers all finished
        __builtin_amdgcn_sched_barrier(0);

        const unsigned short* Ab = As[ks % 3];
        const unsigned short* Bb = Bs[ks % 3];
        bf16x8 af[4], bfg[4];
#pragma unroll
        for (int i = 0; i < 4; ++i)
            af[i] = *(const bf16x8*)&Ab[(wr + i * 16 + fr) * 32 + swk];
#pragma unroll
        for (int j = 0; j < 4; ++j)
            bfg[j] = *(const bf16x8*)&Bb[(wc + j * 16 + fr) * 32 + swk];

        if (ks + 2 < nk) STAGE(ks + 2, (ks + 2) % 3);   // overwrites buf[ks-1]

        __builtin_amdgcn_s_setprio(1);
#pragma unroll
        for (int i = 0; i < 4; ++i)
#pragma unroll
            for (int j = 0; j < 4; ++j)
                acc[i][j] = __builtin_amdgcn_mfma_f32_16x16x32_bf16(af[i], bfg[j], acc[i][j], 0, 0, 0);
        __builtin_amdgcn_s_setprio(0);
    }

    const int r4 = hi * 4;
    if constexpr (FUSED) {
        const int part = (n0 >> 7) % 3;          // 0=q 1=k 2=v
        const int head = n0 / 384;
        const int bh   = (m0 >> 11) * NHEAD + head;
        if (part == 2) {
            // V: transposed write, 4 consecutive t per frag -> ushort4
#pragma unroll
            for (int i = 0; i < 4; ++i) {
                const int t0v = (m0 & (T_DIM - 1)) + wr + i * 16 + r4;
#pragma unroll
                for (int j = 0; j < 4; ++j) {
                    const int d = wc + j * 16 + fr;
                    const float bv = bias[n0 + d];
                    ushort4 o = make_ushort4(f2bf(acc[i][j][0] + bv), f2bf(acc[i][j][1] + bv),
                                             f2bf(acc[i][j][2] + bv), f2bf(acc[i][j][3] + bv));
                    *(ushort4*)&Vt[((size_t)bh * HS + d) * T_DIM + t0v] = o;
                }
            }
        } else {
            unsigned short* Dst = part ? Kb : Qb;
            if (wc == 0) {
                // rope lanes: cols d=j*16+fr (j<2) paired with d+32 (j+2)
#pragma unroll
                for (int i = 0; i < 4; ++i) {
#pragma unroll
                    for (int q = 0; q < 4; ++q) {
                        const int t = (m0 & (T_DIM - 1)) + wr + i * 16 + r4 + q;
                        const float* crow = &cosb[t * 64];
                        const float* srw  = &sinb[t * 64];
                        unsigned short* drow = &Dst[((size_t)bh * T_DIM + t) * HS];
#pragma unroll
                        for (int j = 0; j < 2; ++j) {
                            const int d = j * 16 + fr;
                            const float v1 = acc[i][j][q]     + bias[n0 + d];
                            const float v2 = acc[i][j + 2][q] + bias[n0 + d + 32];
                            drow[d]      = f2bf(v1 * crow[d]      - v2 * srw[d]);
                            drow[d + 32] = f2bf(v2 * crow[d + 32] + v1 * srw[d + 32]);
                        }
                    }
                }
            } else {
                // non-rope lanes: d = 64 + j*16 + fr
#pragma unroll
                for (int i = 0; i < 4; ++i) {
                    const int t0r = (m0 & (T_DIM - 1)) + wr + i * 16 + r4;
#pragma unroll
                    for (int j = 0; j < 4; ++j) {
                        const int d = 64 + j * 16 + fr;
                        const float bv = bias[n0 + d];
                        unsigned short* dcol = &Dst[((size_t)bh * T_DIM + t0r) * HS + d];
#pragma unroll
                        for (int q = 0; q < 4; ++q)
                            dcol[(size_t)q * HS] = f2bf(acc[i][j][q] + bv);
                    }
                }
            }
        }
    } else {
#pragma unroll
        for (int i = 0; i < 4; ++i) {
#pragma unroll
            for (int j = 0; j < 4; ++j) {
                const int col = n0 + wc + j * 16 + fr;
                const float bv = bias[col];
#pragma unroll
                for (int q = 0; q < 4; ++q) {
                    const int row = m0 + wr + i * 16 + r4 + q;
                    Cf32[(size_t)row * N + col] = acc[i][j][q] + bv;
                }
            }
        }
    }
}

// ---------------------------------------------------------------------------
// adapter qkv (tiny GEMM, bf16 weights; verified R5)
// ---------------------------------------------------------------------------
__global__ __launch_bounds__(64)
void adapter_qkv_kernel(const float* __restrict__ wte, const unsigned short* __restrict__ wb,
                        const float* __restrict__ bias, float* __restrict__ aqkv) {
    const int n = blockIdx.x;
    const int lane = threadIdx.x;
    float acc[AT];
#pragma unroll
    for (int a = 0; a < AT; ++a) acc[a] = 0.f;
    for (int k = lane * 8; k < C_DIM; k += 64 * 8) {
        const ushort4 wa = *(const ushort4*)&wb[(size_t)n * C_DIM + k];
        const ushort4 wc = *(const ushort4*)&wb[(size_t)n * C_DIM + k + 4];
        const float w0 = bf2f(wa.x), w1 = bf2f(wa.y), w2 = bf2f(wa.z), w3 = bf2f(wa.w);
        const float w4 = bf2f(wc.x), w5 = bf2f(wc.y), w6 = bf2f(wc.z), w7 = bf2f(wc.w);
#pragma unroll
        for (int a = 0; a < AT; ++a) {
            const float4 t0 = *(const float4*)&wte[(size_t)a * C_DIM + k];
            const float4 t1 = *(const float4*)&wte[(size_t)a * C_DIM + k + 4];
            acc[a] += w0 * t0.x + w1 * t0.y + w2 * t0.z + w3 * t0.w
                    + w4 * t1.x + w5 * t1.y + w6 * t1.z + w7 * t1.w;
        }
    }
#pragma unroll
    for (int a = 0; a < AT; ++a) {
        float v = acc[a];
        for (int off = 32; off; off >>= 1) v += __shfl_down(v, off);
        if (lane == 0) aqkv[(size_t)a * QKV_N + n] = v + bias[n];
    }
}

// ---------------------------------------------------------------------------
// MFMA flash causal attention (verified R5): qt-paired blocks, dbuf staging,
// log2-domain online softmax with defer-max, in-register P redistribution,
// fused adapter attention (BLOCKED aqkv layout), setprio around MFMA.
// ---------------------------------------------------------------------------
__global__ __launch_bounds__(256)
void flash_mfma(const unsigned short* __restrict__ Qb, const unsigned short* __restrict__ Kb,
                const unsigned short* __restrict__ Vt, const float* __restrict__ aqkv,
                const float* __restrict__ gating, unsigned short* __restrict__ yb) {
    __shared__ __align__(16) unsigned short smem[2][16384];   // [buf][K:8192 | V:8192]

    const int tid = threadIdx.x;
    const int wave = tid >> 6, lane = tid & 63;
    const int lo = lane & 15, hi = lane >> 4;

    const int z = blockIdx.x & 15;
    const int h = (blockIdx.x >> 4) & 15;
    const int b = blockIdx.x >> 8;
    const int bh = b * NHEAD + h;
    const float kscale = 0.08838834764831845f * 1.4426950408889634f;  // scale*log2(e)

    const unsigned short* Qh = Qb + (size_t)bh * T_DIM * HS;
    const unsigned short* Kh = Kb + (size_t)bh * T_DIM * HS;
    const unsigned short* Vh = Vt + (size_t)bh * HS * T_DIM;

    float* AK = (float*)&smem[0][0];     // adapter overlay (10x128 f32 x2 = 10KB)
    float* AV = AK + AT * HS;

    auto STAGE = [&](int k0, int bufi) {
        unsigned short* Kd = &smem[bufi][0];
        unsigned short* Vd = &smem[bufi][8192];
#pragma unroll
        for (int t = 0; t < 4; ++t) {
            const int kr = wave * 16 + t * 4 + hi;
            gload_lds16(Kh + (size_t)(k0 + kr) * HS + 8 * (lo ^ (kr & 7)),
                        &Kd[(wave * 16 + t * 4) * 128]);
            const int vr = (wave * 4 + t) * 8 + (lane >> 3);
            gload_lds16(Vh + (size_t)vr * T_DIM + k0 + 8 * ((lane & 7) ^ (vr & 7)),
                        &Vd[(wave * 4 + t) * 8 * 64]);
        }
    };

#pragma unroll 1
    for (int pass = 0; pass < 2; ++pass) {
        const int qt = pass ? z : (31 - z);
        const int q0 = qt * 64;
        const int myqrow = q0 + wave * 16 + lo;

        bf16x8 qf[4];
        {
            const unsigned short* qrow = Qh + (size_t)myqrow * HS;
#pragma unroll
            for (int c = 0; c < 4; ++c) qf[c] = *(const bf16x8*)&qrow[c * 32 + hi * 8];
        }

        f32x4v oacc[8];
#pragma unroll
        for (int d = 0; d < 8; ++d)
#pragma unroll
            for (int q = 0; q < 4; ++q) oacc[d][q] = 0.f;
        float m = -INFINITY, ln = 0.f;

        STAGE(0, 0);
        int cur = 0;
        for (int kt = 0; kt <= qt; ++kt) {
            const int k0 = kt * 64;
            __syncthreads();
            if (kt < qt) STAGE(k0 + 64, cur ^ 1);
            const unsigned short* Ks = &smem[cur][0];
            const unsigned short* Vs = &smem[cur][8192];

            f32x4v sacc[4];
            __builtin_amdgcn_s_setprio(1);
#pragma unroll
            for (int s = 0; s < 4; ++s) {
#pragma unroll
                for (int q = 0; q < 4; ++q) sacc[s][q] = 0.f;
                const int krow = s * 16 + lo;
                const int rs = (lo & 7) << 4;
#pragma unroll
                for (int c = 0; c < 4; ++c) {
                    const int boff = (c * 64 + hi * 16) ^ rs;
                    bf16x8 kf = *(const bf16x8*)&Ks[krow * 128 + (boff >> 1)];
                    sacc[s] = __builtin_amdgcn_mfma_f32_16x16x32_bf16(kf, qf[c], sacc[s], 0, 0, 0);
                }
            }
            __builtin_amdgcn_s_setprio(0);

            const bool dtile = (kt == qt);
            float p[4][4];
            float xm = -INFINITY;
#pragma unroll
            for (int s = 0; s < 4; ++s)
#pragma unroll
                for (int q = 0; q < 4; ++q) {
                    float v = sacc[s][q] * kscale;
                    if (dtile && (k0 + s * 16 + hi * 4 + q > myqrow)) v = -INFINITY;
                    p[s][q] = v;
                    xm = fmaxf(xm, v);
                }
            xm = fmaxf(xm, __shfl_xor(xm, 16));
            xm = fmaxf(xm, __shfl_xor(xm, 32));
            if (__any(xm > m + 11.5f)) {
                const float mnew = fmaxf(m, xm);
                const float al = exp2f(m - mnew);
                m = mnew;
                ln *= al;
                float aq[4];
#pragma unroll
                for (int q = 0; q < 4; ++q) aq[q] = __shfl(al, hi * 4 + q);
#pragma unroll
                for (int d = 0; d < 8; ++d)
#pragma unroll
                    for (int q = 0; q < 4; ++q) oacc[d][q] *= aq[q];
            }
            float psum = 0.f;
#pragma unroll
            for (int s = 0; s < 4; ++s)
#pragma unroll
                for (int q = 0; q < 4; ++q) {
                    p[s][q] = exp2f(p[s][q] - m);
                    psum += p[s][q];
                }
            psum += __shfl_xor(psum, 16);
            psum += __shfl_xor(psum, 32);
            ln += psum;

            unsigned int pk[4][2];
#pragma unroll
            for (int s = 0; s < 4; ++s) {
                pk[s][0] = pack_bf16(p[s][0], p[s][1]);
                pk[s][1] = pack_bf16(p[s][2], p[s][3]);
            }
            const int src0 = lo + ((hi & 1) << 5);
            const int src1 = src0 + 16;
            const bool shi = (hi >> 1) != 0;
#pragma unroll
            for (int c = 0; c < 2; ++c) {
                const unsigned int a0 = (unsigned int)__shfl((int)pk[c*2][0], src0);
                const unsigned int b0 = (unsigned int)__shfl((int)pk[c*2+1][0], src0);
                const unsigned int a1 = (unsigned int)__shfl((int)pk[c*2][1], src0);
                const unsigned int b1 = (unsigned int)__shfl((int)pk[c*2+1][1], src0);
                const unsigned int a2 = (unsigned int)__shfl((int)pk[c*2][0], src1);
                const unsigned int b2 = (unsigned int)__shfl((int)pk[c*2+1][0], src1);
                const unsigned int a3 = (unsigned int)__shfl((int)pk[c*2][1], src1);
                const unsigned int b3 = (unsigned int)__shfl((int)pk[c*2+1][1], src1);
                union { unsigned int u[4]; bf16x8 v; } cv2;
                cv2.u[0] = shi ? b0 : a0;
                cv2.u[1] = shi ? b1 : a1;
                cv2.u[2] = shi ? b2 : a2;
                cv2.u[3] = shi ? b3 : a3;
                const bf16x8 pf = cv2.v;
                __builtin_amdgcn_s_setprio(1);
#pragma unroll
                for (int d = 0; d < 8; ++d) {
                    const int vrow = d * 16 + lo;
                    const int boff = (c * 64 + hi * 16) ^ ((lo & 7) << 4);
                    bf16x8 vf = *(const bf16x8*)&Vs[vrow * 64 + (boff >> 1)];
                    oacc[d] = __builtin_amdgcn_mfma_f32_16x16x32_bf16(pf, vf, oacc[d], 0, 0, 0);
                }
                __builtin_amdgcn_s_setprio(0);
            }
            cur ^= 1;
        }

        float linv[4];
#pragma unroll
        for (int q = 0; q < 4; ++q) linv[q] = 1.f / __shfl(ln, hi * 4 + q);
#pragma unroll
        for (int d = 0; d < 8; ++d)
#pragma unroll
            for (int q = 0; q < 4; ++q) oacc[d][q] *= linv[q];

        // ---- adapter attention (10 keys, unmasked; BLOCKED aqkv layout) ----
        __syncthreads();
        for (int idx = tid; idx < AT * HS; idx += 256) {
            const int a = idx >> 7, d = idx & 127;
            AK[idx] = aqkv[(size_t)a * QKV_N + C_DIM + h * HS + d];
            AV[idx] = aqkv[(size_t)a * QKV_N + 2 * C_DIM + h * HS + d];
        }
        __syncthreads();

        float qflt[4][8];
#pragma unroll
        for (int c = 0; c < 4; ++c)
#pragma unroll
            for (int j = 0; j < 8; ++j) qflt[c][j] = bf2f((unsigned short)qf[c][j]);

        float e[AT];
        float amax = -INFINITY;
#pragma unroll
        for (int a = 0; a < AT; ++a) {
            float t = 0.f;
#pragma unroll
            for (int c = 0; c < 4; ++c) {
                const float4 k0v = *(const float4*)&AK[a * HS + c * 32 + hi * 8];
                const float4 k1v = *(const float4*)&AK[a * HS + c * 32 + hi * 8 + 4];
                t += qflt[c][0] * k0v.x + qflt[c][1] * k0v.y + qflt[c][2] * k0v.z + qflt[c][3] * k0v.w
                   + qflt[c][4] * k1v.x + qflt[c][5] * k1v.y + qflt[c][6] * k1v.z + qflt[c][7] * k1v.w;
            }
            t += __shfl_xor(t, 16);
            t += __shfl_xor(t, 32);
            e[a] = t * 0.08838834764831845f;
            amax = fmaxf(amax, e[a]);
        }
        float asum = 0.f;
#pragma unroll
        for (int a = 0; a < AT; ++a) { e[a] = __expf(e[a] - amax); asum += e[a]; }
        const float gcoef = gating[0] / asum;

#pragma unroll
        for (int a = 0; a < AT; ++a) {
            const float ca = e[a] * gcoef;
            float cq[4];
#pragma unroll
            for (int q = 0; q < 4; ++q) cq[q] = __shfl(ca, hi * 4 + q);
#pragma unroll
            for (int d = 0; d < 8; ++d) {
                const float av = AV[a * HS + d * 16 + lo];
#pragma unroll
                for (int q = 0; q < 4; ++q) oacc[d][q] += cq[q] * av;
            }
        }

#pragma unroll
        for (int q = 0; q < 4; ++q) {
            const int row = q0 + wave * 16 + hi * 4 + q;
            unsigned short* dst = yb + ((size_t)(b * T_DIM + row)) * C_DIM + h * HS + lo;
#pragma unroll
            for (int d = 0; d < 8; ++d) dst[d * 16] = f2bf(oacc[d][q]);
        }

        if (pass == 0) __syncthreads();
    }
}

// ---------------------------------------------------------------------------
extern "C" void kernel_launch(void* const* d_in, const int* in_sizes, int n_in,
                              void* d_out, int out_size, void* d_ws, size_t ws_size,
                              hipStream_t stream) {
    const float* x       = (const float*)d_in[0];
    const float* cosb    = (const float*)d_in[1];
    const float* sinb    = (const float*)d_in[2];
    // d_in[3] = mask (causal, unused)
    const float* attn_w  = (const float*)d_in[4];
    const float* attn_b  = (const float*)d_in[5];
    const float* proj_w  = (const float*)d_in[6];
    const float* proj_b  = (const float*)d_in[7];
    const float* wte     = (const float*)d_in[8];
    const float* gating  = (const float*)d_in[9];
    float* out = (float*)d_out;

    // workspace (~118 MB): aqkv | xb | awb | Qb | Kb | Vt | pwb | yv
    float* aqkv = (float*)d_ws;
    unsigned short* xb  = (unsigned short*)(aqkv + (size_t)AT * QKV_N);
    unsigned short* awb = xb  + (size_t)M_DIM * C_DIM;
    unsigned short* Qb  = awb + (size_t)QKV_N * C_DIM;
    unsigned short* Kb  = Qb  + (size_t)B_DIM * NHEAD * T_DIM * HS;
    unsigned short* Vt  = Kb  + (size_t)B_DIM * NHEAD * T_DIM * HS;
    unsigned short* pwb = Vt  + (size_t)B_DIM * NHEAD * T_DIM * HS;
    unsigned short* yv  = pwb + (size_t)C_DIM * C_DIM;

    // 1. convert x, attn_w to bf16
    f32_to_bf16_kernel<<<(M_DIM * C_DIM / 8 + 255) / 256, 256, 0, stream>>>(x, xb, M_DIM * C_DIM / 8);
    f32_to_bf16_kernel<<<(QKV_N * C_DIM / 8 + 255) / 256, 256, 0, stream>>>(attn_w, awb, QKV_N * C_DIM / 8);
    // 2. fused qkv GEMM: bias + RoPE + repack -> Qb/Kb/Vt directly
    gemm_pipe<1><<<dim3(QKV_N / 128, M_DIM / 128), 256, 0, stream>>>(
        xb, awb, attn_b, nullptr, cosb, sinb, Qb, Kb, Vt, M_DIM, QKV_N, C_DIM);
    // 3. adapter qkv (bf16 weights)
    adapter_qkv_kernel<<<QKV_N, 64, 0, stream>>>(wte, awb, attn_b, aqkv);
    // 4. convert proj_w
    f32_to_bf16_kernel<<<(C_DIM * C_DIM / 8 + 255) / 256, 256, 0, stream>>>(proj_w, pwb, C_DIM * C_DIM / 8);
    // 5. MFMA flash attention + adapter + gating -> yv (bf16)
    flash_mfma<<<B_DIM * NHEAD * 16, 256, 0, stream>>>(Qb, Kb, Vt, aqkv, gating, yv);
    // 6. out = y @ proj_w^T + proj_b (f32 out)
    gemm_pipe<0><<<dim3(C_DIM / 128, M_DIM / 128), 256, 0, stream>>>(
        yv, pwb, proj_b, out, nullptr, nullptr, nullptr, nullptr, nullptr, M_DIM, C_DIM, C_DIM);
}